// Round 11
// baseline (583.557 us; speedup 1.0000x reference)
//
#include <hip/hip_runtime.h>
#include <hip/hip_fp16.h>
#include <cstdint>
#include <cstddef>

// VideoSAGE: prep(weights) -> proj GEMM -> FUSED 3-layer GCN -> fused head.
// fp16 MFMA 16x16x32, fp32 accum.
// R5-R8 PM: tile/occupancy bounced off ~20-29 B/cyc/CU ingress; lever = BYTES.
// R9/R10 (WIN 211->198): halo-LDS band-blend, 64x256 proj.
// R12 PM (272us): fused GCN spilled at VGPR cap 128 (acc[3][8]=96) -> 65MB
//   scratch; + ~7M LDS conflict cycles.
// R13/R14 PM (535us): lb(1024,4) made it WORSE: allocator budgeted 32
//   waves/CU -> VGPR cap 64 (reported exactly 64). acc(48) spilled and the
//   K-loop RE-READS spilled acc every step: FETCH 1.19GB/dispatch (20x R12),
//   WRITE 157MB, dur 410us. Conflict count ~7M unchanged by sW swizzle change
//   -> conflicts are inherent b128 behavior (~12us), not the sW pattern.
// R15: lb(1024, 1) -- under EITHER second-arg semantics (blocks/CU or min
//   waves/EU) the cap is 128 (16 waves = 4/SIMD floor). acc(48)+af(12)+bf(16)
//   +addr ~110 fits. Dropped rP/rN/rS arrays (recompute inline, -9 VGPR).
// Falsifiers: VGPR ~110-128, FETCH ~25MB, WRITE ~17MB, dur 25-40us.

typedef _Float16 f16;
typedef _Float16 f16x8 __attribute__((ext_vector_type(8)));
typedef float    f32x4 __attribute__((ext_vector_type(4)));

__device__ __forceinline__ void async_cp16(const void* g, void* l) {
  __builtin_amdgcn_global_load_lds((const __attribute__((address_space(1))) void*)g,
                                   (__attribute__((address_space(3))) void*)l, 16, 0, 0);
}

__device__ __forceinline__ f16x8 splat8(f16 v) {
  f16x8 r;
#pragma unroll
  for (int e = 0; e < 8; ++e) r[e] = v;
  return r;
}

// ---------------------------------------------------------------------------
// Proj GEMM: C[M,N] = A(fp32)*BT^T + bias, cvt fp32->f16 in A staging.
// R9-verified geometry: BM=64, BN=256, 512 thr (2x4 waves), grid (M/64, 2).
// ---------------------------------------------------------------------------
template<int BM, int BN, bool RELU, bool HAS_BIAS>
__global__ __launch_bounds__(512, 4) void proj_gemm_kernel(
    const float* __restrict__ Aptr, const f16* __restrict__ BT,
    f16* __restrict__ C, const float* __restrict__ bias,
    int M, int N, int K)
{
  constexpr int BK = 64;
  constexpr int NT = 512;
  constexpr int WAVES_N = 4;
  constexpr int WM = BM / 2;         // 32
  constexpr int WN = BN / WAVES_N;   // 64
  constexpr int TM = WM / 16;        // 2
  constexpr int TN = WN / 16;        // 4
  constexpr int ITER_B = (BN * BK) / (NT * 8);   // 4

  __shared__ __align__(16) f16 sA[BM * BK];
  __shared__ __align__(16) f16 sB[BN * BK];

  const int tid  = threadIdx.x;
  const int lane = tid & 63;
  const int wave = tid >> 6;
  const int wm   = wave / WAVES_N;
  const int wn   = wave % WAVES_N;
  const int m0   = blockIdx.x * BM;
  const int n0   = blockIdx.y * BN;
  const int quad = lane >> 4;
  const int l16  = lane & 15;

  uint32_t offA;
  {
    const int row = tid >> 3;
    const int q   = (tid & 7) ^ (row & 7);
    offA = (uint32_t)(((size_t)(m0 + row) * K + q * 8) * 4);
  }

  f32x4 acc[TM][TN];
#pragma unroll
  for (int i = 0; i < TM; ++i)
#pragma unroll
    for (int j = 0; j < TN; ++j)
      acc[i][j] = (f32x4){0.f, 0.f, 0.f, 0.f};

  float4 pa0, pa1;
  {
    const float4* p = (const float4*)((const char*)Aptr + offA);
    pa0 = p[0]; pa1 = p[1];
  }

  for (int kt = 0; kt < K; kt += BK) {
#pragma unroll
    for (int j = 0; j < ITER_B; ++j) {
      const int linear = j * NT + tid;
      const int row = linear >> 3;
      const int q   = (linear & 7) ^ (row & 7);
      async_cp16(BT + (size_t)(n0 + row) * K + kt + q * 8, &sB[linear * 8]);
    }
    {
      f16x8 o;
      o[0] = (f16)pa0.x; o[1] = (f16)pa0.y; o[2] = (f16)pa0.z; o[3] = (f16)pa0.w;
      o[4] = (f16)pa1.x; o[5] = (f16)pa1.y; o[6] = (f16)pa1.z; o[7] = (f16)pa1.w;
      *(f16x8*)&sA[(size_t)tid * 8] = o;
    }
    __syncthreads();   // barrier1

    if (kt + BK < K) {   // prefetch next A-regs; drains at barrier2
      const float4* p = (const float4*)((const char*)Aptr + (size_t)(kt + BK) * 4 + offA);
      pa0 = p[0]; pa1 = p[1];
    }

#pragma unroll
    for (int kk = 0; kk < 2; ++kk) {
      const int c = quad + kk * 4;
      f16x8 af[TM], bf[TN];
#pragma unroll
      for (int mi = 0; mi < TM; ++mi) {
        const int ml = wm * WM + mi * 16 + l16;
        af[mi] = *(const f16x8*)&sA[ml * 64 + ((c ^ (ml & 7)) * 8)];
      }
#pragma unroll
      for (int ni = 0; ni < TN; ++ni) {
        const int nl = wn * WN + ni * 16 + l16;
        bf[ni] = *(const f16x8*)&sB[nl * 64 + ((c ^ (nl & 7)) * 8)];
      }
#pragma unroll
      for (int mi = 0; mi < TM; ++mi)
#pragma unroll
        for (int ni = 0; ni < TN; ++ni)
          acc[mi][ni] = __builtin_amdgcn_mfma_f32_16x16x32_f16(
              af[mi], bf[ni], acc[mi][ni], 0, 0, 0);
    }
    __syncthreads();   // barrier2
  }

#pragma unroll
  for (int ni = 0; ni < TN; ++ni) {
    const int nc = n0 + wn * WN + ni * 16 + l16;
    const float bv = HAS_BIAS ? bias[nc] : 0.0f;
#pragma unroll
    for (int mi = 0; mi < TM; ++mi) {
#pragma unroll
      for (int r = 0; r < 4; ++r) {
        const int mr = m0 + wm * WM + mi * 16 + quad * 4 + r;
        float v = acc[mi][ni][r] + bv;
        if (RELU) v = fmaxf(v, 0.0f);
        C[(size_t)mr * N + nc] = (f16)v;
      }
    }
  }
}

// ---------------------------------------------------------------------------
// Fused 3-layer GCN: h_out = L3(relu(L2(relu(L1(h_in))))), layer = band(h)@W+b.
// Block: 96-row h-tile (64 out + 16 halo/side) x H=512 in LDS (96KB) + 32KB
// W slice = 128KB. 1024 thr = 16 waves (2M x 8N): wave = 48 rows x 64 cols,
// TM=3, TN=4 -> acc 48 VGPR; lb(1024,1) -> VGPR cap 128, no spills.
// Contamination: halo-edge error reaches <=1 row/layer (<=3 total) << 16
// margin; batch edges exact via zero band coefs (cpf=0@s=0, cnf=0@s=S-1).
// ---------------------------------------------------------------------------
__global__ __launch_bounds__(1024, 1) void gcn_fused_kernel(
    const f16* __restrict__ hin, const f16* __restrict__ GT,
    const float* __restrict__ gb, f16* __restrict__ hout, int M)
{
  constexpr int ROWS = 96, HALO = 16, BK = 32, S = 2048;
  constexpr int H = 512;
  constexpr int TM = 3, TN = 4;

  __shared__ __align__(16) f16 sh[ROWS * H];    // 96 KB
  __shared__ __align__(16) f16 sW[H * BK];      // 32 KB

  const int tid  = threadIdx.x;
  const int lane = tid & 63;
  const int wave = tid >> 6;         // 0..15
  const int wm   = wave >> 3;        // 0..1
  const int wn   = wave & 7;         // 0..7
  const int quad = lane >> 4;
  const int l16  = lane & 15;
  const int m0   = blockIdx.x * 64;

  const float dM = 0.57735026919f;   // (3+1e-8)^-1/2
  const float dE = 0.70710678118f;   // (2+1e-8)^-1/2

  // per-lane band coefs for the TM A-fragment rows (rows recomputed inline)
  f16 cf[TM][3];
#pragma unroll
  for (int mi = 0; mi < TM; ++mi) {
    const int lr = wm * 48 + mi * 16 + l16;     // 0..95
    const int g  = m0 - HALO + lr;
    const int s  = g & (S - 1);
    const float dsv = (s == 0 || s == S - 1) ? dE : dM;
    cf[mi][0] = (f16)((s > 0)     ? dsv * ((s - 1 == 0) ? dE : dM)     : 0.0f);
    cf[mi][1] = (f16)(dsv * dsv);
    cf[mi][2] = (f16)((s < S - 1) ? dsv * ((s + 1 == S - 1) ? dE : dM) : 0.0f);
  }

  // ---- stage h rows [m0-16, m0+80) clamped, 64 chunks/row, XOR(row&7) ----
#pragma unroll
  for (int j = 0; j < 6; ++j) {
    const int linear = j * 1024 + tid;   // 0..6143
    const int row = linear >> 6;         // 0..95
    const int cin = linear & 63;
    const int qq  = cin ^ (row & 7);
    int g = m0 - HALO + row;
    g = g < 0 ? 0 : (g >= M ? M - 1 : g);
    async_cp16(hin + (size_t)g * H + qq * 8, &sh[(size_t)linear * 8]);
  }

  for (int L = 0; L < 3; ++L) {
    const f16* WL = GT + (size_t)L * 262144;
    const float* bL = gb + L * 512;

    f32x4 acc[TM][TN];
#pragma unroll
    for (int i = 0; i < TM; ++i)
#pragma unroll
      for (int j = 0; j < TN; ++j)
        acc[i][j] = (f32x4){0.f, 0.f, 0.f, 0.f};

    for (int kt = 0; kt < H; kt += BK) {
      // stage W slice [512][kt:kt+32], 4 chunks/row, XOR((row>>1)&3)
#pragma unroll
      for (int j = 0; j < 2; ++j) {
        const int linear = j * 1024 + tid;   // 0..2047
        const int row = linear >> 2;
        const int cin = linear & 3;
        const int qq  = cin ^ ((row >> 1) & 3);
        async_cp16(WL + (size_t)row * H + kt + qq * 8, &sW[(size_t)linear * 8]);
      }
      __syncthreads();   // barrier1: sW ready (sh ready on first step)

      const int cb = kt >> 3;
      const int c  = cb + quad;
      f16x8 af[TM], bf[TN];
#pragma unroll
      for (int mi = 0; mi < TM; ++mi) {
        const int lr = wm * 48 + mi * 16 + l16;          // recompute (VGPR relief)
        const int rp = (lr > 0)        ? lr - 1 : 0;
        const int rn = (lr < ROWS - 1) ? lr + 1 : ROWS - 1;
        f16x8 pv = *(const f16x8*)&sh[rp * H + ((c ^ (rp & 7)) * 8)];
        f16x8 sv = *(const f16x8*)&sh[lr * H + ((c ^ (lr & 7)) * 8)];
        f16x8 nv = *(const f16x8*)&sh[rn * H + ((c ^ (rn & 7)) * 8)];
        f16x8 r = pv * splat8(cf[mi][0]);
        r += sv * splat8(cf[mi][1]);
        r += nv * splat8(cf[mi][2]);
        af[mi] = r;
      }
#pragma unroll
      for (int ni = 0; ni < TN; ++ni) {
        const int nl = wn * 64 + ni * 16 + l16;
        bf[ni] = *(const f16x8*)&sW[nl * BK + ((quad ^ ((nl >> 1) & 3)) * 8)];
      }
#pragma unroll
      for (int mi = 0; mi < TM; ++mi)
#pragma unroll
        for (int ni = 0; ni < TN; ++ni)
          acc[mi][ni] = __builtin_amdgcn_mfma_f32_16x16x32_f16(
              af[mi], bf[ni], acc[mi][ni], 0, 0, 0);
      __syncthreads();   // barrier2: sW consumed, sh reads done
    }

    // ---- epilogue ----
    if (L < 2) {
      // write relu(acc+bias) back into sh in place (reads drained at b2;
      // visibility for next layer ensured by its barrier1)
#pragma unroll
      for (int ni = 0; ni < TN; ++ni) {
        const int nc = wn * 64 + ni * 16 + l16;
        const int chunk = nc >> 3;
        const float bv = bL[nc];
#pragma unroll
        for (int mi = 0; mi < TM; ++mi) {
#pragma unroll
          for (int r = 0; r < 4; ++r) {
            const int row = wm * 48 + mi * 16 + quad * 4 + r;
            const float v = fmaxf(acc[mi][ni][r] + bv, 0.0f);
            sh[row * H + ((chunk ^ (row & 7)) * 8) + (nc & 7)] = (f16)v;
          }
        }
      }
    } else {
      // final layer: store rows 16..79 -> hout[m0 .. m0+64)
#pragma unroll
      for (int ni = 0; ni < TN; ++ni) {
        const int nc = wn * 64 + ni * 16 + l16;
        const float bv = bL[nc];
#pragma unroll
        for (int mi = 0; mi < TM; ++mi) {
#pragma unroll
          for (int r = 0; r < 4; ++r) {
            const int lr = wm * 48 + mi * 16 + quad * 4 + r;
            if (lr >= HALO && lr < HALO + 64) {
              const float v = acc[mi][ni][r] + bv;
              hout[(size_t)(m0 + lr - HALO) * H + nc] = (f16)v;
            }
          }
        }
      }
    }
  }
}

// ---------------------------------------------------------------------------
// Fused head, 32 rows/block (512 blocks): z1[32][256] LDS -> z2[32][128] LDS
// -> sigmoid dot. Total ~53.8KB -> 2 blocks/CU.
// ---------------------------------------------------------------------------
__global__ __launch_bounds__(256) void head_fused_kernel(
    const f16* __restrict__ h, const f16* __restrict__ S1T,
    const f16* __restrict__ S2T,
    const float* __restrict__ s1b, const float* __restrict__ s2b,
    const float* __restrict__ s3w, const float* __restrict__ s3b,
    float* __restrict__ out)
{
  __shared__ __align__(16) char smem[36864 + 32 * 264 * 2];
  f16* sA  = (f16*)smem;             // [32*64]   = 4KB
  f16* sB  = (f16*)(smem + 4096);    // [256*64]  = 32KB
  f16* zs  = (f16*)(smem + 36864);   // [32][264]
  f16* z2s = (f16*)smem;             // [32][136] = 8.5KB (reuses sA+sB head)
  f16* sB2 = (f16*)(smem + 8704);    // [128*64]  = 16KB

  const int tid  = threadIdx.x;
  const int lane = tid & 63;
  const int wave = tid >> 6;
  const int quad = lane >> 4;
  const int l16  = lane & 15;
  const int m0   = blockIdx.x * 32;

  // ---- GEMM1: z1[32][256] = relu(h[32x512] @ S1T^T + s1b); wave = 32x64 ----
  f32x4 acc[2][4];
#pragma unroll
  for (int i = 0; i < 2; ++i)
#pragma unroll
    for (int j = 0; j < 4; ++j) acc[i][j] = (f32x4){0.f, 0.f, 0.f, 0.f};

  for (int kt = 0; kt < 512; kt += 64) {
    __syncthreads();
    {   // A: 32x64 halfs = 256 chunks, 1 iter
      const int linear = tid;
      const int row = linear >> 3;
      const int q   = (linear & 7) ^ (row & 7);
      async_cp16(h + (size_t)(m0 + row) * 512 + kt + q * 8, &sA[linear * 8]);
    }
#pragma unroll
    for (int j = 0; j < 8; ++j) {   // B: 256x64 halfs = 2048 chunks
      const int linear = j * 256 + tid;
      const int row = linear >> 3;
      const int q   = (linear & 7) ^ (row & 7);
      async_cp16(S1T + (size_t)row * 512 + kt + q * 8, &sB[linear * 8]);
    }
    __syncthreads();
#pragma unroll
    for (int kk = 0; kk < 2; ++kk) {
      const int c = quad + kk * 4;
      f16x8 af[2], bf[4];
#pragma unroll
      for (int mi = 0; mi < 2; ++mi) {
        const int ml = mi * 16 + l16;
        af[mi] = *(const f16x8*)&sA[ml * 64 + ((c ^ (ml & 7)) * 8)];
      }
#pragma unroll
      for (int ni = 0; ni < 4; ++ni) {
        const int nl = wave * 64 + ni * 16 + l16;
        bf[ni] = *(const f16x8*)&sB[nl * 64 + ((c ^ (nl & 7)) * 8)];
      }
#pragma unroll
      for (int mi = 0; mi < 2; ++mi)
#pragma unroll
        for (int ni = 0; ni < 4; ++ni)
          acc[mi][ni] = __builtin_amdgcn_mfma_f32_16x16x32_f16(
              af[mi], bf[ni], acc[mi][ni], 0, 0, 0);
    }
  }
#pragma unroll
  for (int ni = 0; ni < 4; ++ni) {
    const int nc = wave * 64 + ni * 16 + l16;
    const float bv = s1b[nc];
#pragma unroll
    for (int mi = 0; mi < 2; ++mi)
#pragma unroll
      for (int r = 0; r < 4; ++r) {
        const int row = mi * 16 + quad * 4 + r;
        zs[row * 264 + nc] = (f16)fmaxf(acc[mi][ni][r] + bv, 0.0f);
      }
  }
  __syncthreads();

  // ---- GEMM2: z2[32][128] = relu(z1 @ S2T^T + s2b); wave = 32x32 ----
  f32x4 acc2[2][2];
#pragma unroll
  for (int i = 0; i < 2; ++i)
#pragma unroll
    for (int j = 0; j < 2; ++j) acc2[i][j] = (f32x4){0.f, 0.f, 0.f, 0.f};

  for (int kt2 = 0; kt2 < 4; ++kt2) {
    __syncthreads();
#pragma unroll
    for (int j = 0; j < 4; ++j) {   // B2: 128x64 halfs = 1024 chunks
      const int linear = j * 256 + tid;
      const int row = linear >> 3;
      const int q   = (linear & 7) ^ (row & 7);
      async_cp16(S2T + (size_t)row * 256 + kt2 * 64 + q * 8, &sB2[linear * 8]);
    }
    __syncthreads();
#pragma unroll
    for (int kk = 0; kk < 2; ++kk) {
      const int c = quad + kk * 4;
      f16x8 af[2], bf[2];
#pragma unroll
      for (int mi = 0; mi < 2; ++mi) {
        const int row = mi * 16 + l16;
        af[mi] = *(const f16x8*)&zs[row * 264 + (kt2 * 8 + c) * 8];
      }
#pragma unroll
      for (int ni = 0; ni < 2; ++ni) {
        const int nl = wave * 32 + ni * 16 + l16;
        bf[ni] = *(const f16x8*)&sB2[nl * 64 + ((c ^ (nl & 7)) * 8)];
      }
#pragma unroll
      for (int mi = 0; mi < 2; ++mi)
#pragma unroll
        for (int ni = 0; ni < 2; ++ni)
          acc2[mi][ni] = __builtin_amdgcn_mfma_f32_16x16x32_f16(
              af[mi], bf[ni], acc2[mi][ni], 0, 0, 0);
    }
  }
  __syncthreads();
#pragma unroll
  for (int ni = 0; ni < 2; ++ni) {
    const int nc = wave * 32 + ni * 16 + l16;
    const float bv = s2b[nc];
#pragma unroll
    for (int mi = 0; mi < 2; ++mi)
#pragma unroll
      for (int r = 0; r < 4; ++r) {
        const int row = mi * 16 + quad * 4 + r;
        z2s[row * 136 + nc] = (f16)fmaxf(acc2[mi][ni][r] + bv, 0.0f);
      }
  }
  __syncthreads();

  // ---- out[m] = sigmoid(dot(z2[m,:128], w) + b), 8 threads/row ----
  const int m  = tid >> 3;
  const int qd = tid & 7;
  float p = 0.f;
#pragma unroll
  for (int j = 0; j < 2; ++j) {
    f16x8 v = *(const f16x8*)&z2s[m * 136 + qd * 16 + j * 8];
#pragma unroll
    for (int e = 0; e < 8; ++e) p += (float)v[e] * s3w[qd * 16 + j * 8 + e];
  }
  p += __shfl_xor(p, 1);
  p += __shfl_xor(p, 2);
  p += __shfl_xor(p, 4);
  if (qd == 0) out[m0 + m] = 1.0f / (1.0f + expf(-(p + s3b[0])));
}

// ---------------------------------------------------------------------------
// Prep: 64x64 LDS tile-transposes of all weights (coalesced both sides).
// ---------------------------------------------------------------------------
__global__ __launch_bounds__(256) void prep_kernel(
    const float* __restrict__ Wp, f16* __restrict__ WpT,
    const float* __restrict__ gW, f16* __restrict__ GT,
    const float* __restrict__ s1W, f16* __restrict__ S1T,
    const float* __restrict__ s2W, f16* __restrict__ S2T)
{
  __shared__ f16 s[64 * 68];
  const int tid = threadIdx.x;
  int b = blockIdx.x;

  const float* W; f16* WT; int K, N, tile;
  if (b < 128)      { W = Wp;  WT = WpT; K = 1024; N = 512; tile = b; }
  else if (b < 320) { const int i = (b - 128) >> 6;
                      W = gW + (size_t)i * 262144; WT = GT + (size_t)i * 262144;
                      K = 512; N = 512; tile = (b - 128) & 63; }
  else if (b < 352) { W = s1W; WT = S1T; K = 512; N = 256; tile = b - 320; }
  else              { W = s2W; WT = S2T; K = 256; N = 128; tile = b - 352; }

  const int nt = tile % (N >> 6);
  const int kt = tile / (N >> 6);
#pragma unroll
  for (int it = 0; it < 16; ++it) {
    const int i  = it * 256 + tid;
    const int rk = i >> 6, rn = i & 63;
    s[rn * 68 + rk] = (f16)W[(size_t)(kt * 64 + rk) * N + nt * 64 + rn];
  }
  __syncthreads();
#pragma unroll
  for (int it = 0; it < 16; ++it) {
    const int i  = it * 256 + tid;
    const int rn = i >> 6, rk = i & 63;
    WT[(size_t)(nt * 64 + rn) * K + kt * 64 + rk] = s[rn * 68 + rk];
  }
}

// ---------------------------------------------------------------------------
extern "C" void kernel_launch(void* const* d_in, const int* in_sizes, int n_in,
                              void* d_out, int out_size, void* d_ws, size_t ws_size,
                              hipStream_t stream) {
  (void)in_sizes; (void)n_in; (void)out_size; (void)ws_size;
  const float* x   = (const float*)d_in[0];
  const float* Wp  = (const float*)d_in[1];
  const float* bp  = (const float*)d_in[2];
  const float* gW  = (const float*)d_in[3];
  const float* gb  = (const float*)d_in[4];
  const float* s1W = (const float*)d_in[5];
  const float* s1b = (const float*)d_in[6];
  const float* s2W = (const float*)d_in[7];
  const float* s2b = (const float*)d_in[8];
  const float* s3W = (const float*)d_in[9];
  const float* s3b = (const float*)d_in[10];
  float* out = (float*)d_out;

  constexpr int M = 16384;
  char* ws = (char*)d_ws;
  f16* hA  = (f16*)(ws + 0);            // 16384x512
  f16* hB  = (f16*)(ws + 16777216);     // 16384x512
  f16* WpT = (f16*)(ws + 33554432);     // [512,1024]
  f16* GT  = (f16*)(ws + 34603008);     // 3x[512,512]
  f16* S1T = (f16*)(ws + 36175872);     // [256,512]
  f16* S2T = (f16*)(ws + 36438016);     // [128,256]

  prep_kernel<<<360, 256, 0, stream>>>(Wp, WpT, gW, GT, s1W, S1T, s2W, S2T);

  // proj: hA = x @ Wp + bp  (R9-verified geometry)
  proj_gemm_kernel<64, 256, false, true>
      <<<dim3(M / 64, 2), 512, 0, stream>>>(x, WpT, hA, bp, M, 512, 1024);

  // fused 3-layer GCN: hB = GCN3(hA), all intermediates in LDS
  gcn_fused_kernel<<<M / 64, 1024, 0, stream>>>(hA, GT, gb, hB, M);

  head_fused_kernel<<<M / 32, 256, 0, stream>>>(hB, S1T, S2T, s1b, s2b, s3W, s3b, out);
}

// Round 12
// 199.596 us; speedup vs baseline: 2.9237x; 2.9237x over previous
//
#include <hip/hip_runtime.h>
#include <hip/hip_fp16.h>
#include <cstdint>
#include <cstddef>

// VideoSAGE: prep(weights) -> proj GEMM -> 3x GCN GEMM (128x128 m97-geometry,
// fused exact band mix) -> fused head. fp16 MFMA 16x16x32, fp32 accum.
// R9/R10 (best, 198us): 64x256 proj + halo-LDS band-blend GCN.
// R12-R15 PM (fusion arc, 272/535/583us): 3-layer LDS fusion abandoned --
//   (a) 1024-thr workgroups get VGPR cap 64 on this toolchain REGARDLESS of
//       launch_bounds 2nd arg (two data points) -> acc spills, FETCH 1.3GB;
//   (b) economics were wrong: GCN layers move only ~34MB (~6us) -- never
//       byte-bound; fusion paid 1.5x halo FLOPs for nothing.
// SESSION MODEL: MfmaUtil <=15% everywhere; 50 GFLOP net at ~250TF = ~200us.
//   Lever = MFMA-per-barrier amortization, not bytes.
// R16: GCN -> m97-proven shape: 128x128 tile, 256 thr / 4 waves (2x2),
//   wave 64x64 (acc[4][4]=64 VGPR, ~120 total -> 3-4 waves/SIMD), 32 MFMA/
//   wave/K-step (2x prev). R9-exact band blend kept (2 halo rows, blend at
//   fragment read). Grid (128,4)=512=2/CU, LDS 32.6KB. Proj/head/prep = R9.
// Falsifiers: gcn VGPR 110-130, MfmaUtil>=25%, dur 15-22us each.

typedef _Float16 f16;
typedef _Float16 f16x8 __attribute__((ext_vector_type(8)));
typedef float    f32x4 __attribute__((ext_vector_type(4)));

__device__ __forceinline__ void async_cp16(const void* g, void* l) {
  __builtin_amdgcn_global_load_lds((const __attribute__((address_space(1))) void*)g,
                                   (__attribute__((address_space(3))) void*)l, 16, 0, 0);
}

__device__ __forceinline__ f16x8 splat8(f16 v) {
  f16x8 r;
#pragma unroll
  for (int e = 0; e < 8; ++e) r[e] = v;
  return r;
}

// ---------------------------------------------------------------------------
// Proj GEMM: C[M,N] = A(fp32)*BT^T + bias, cvt fp32->f16 in A staging.
// R9-verified geometry: BM=64, BN=256, 512 thr (2x4 waves), grid (M/64, 2).
// ---------------------------------------------------------------------------
template<int BM, int BN, bool RELU, bool HAS_BIAS>
__global__ __launch_bounds__(512, 4) void proj_gemm_kernel(
    const float* __restrict__ Aptr, const f16* __restrict__ BT,
    f16* __restrict__ C, const float* __restrict__ bias,
    int M, int N, int K)
{
  constexpr int BK = 64;
  constexpr int NT = 512;
  constexpr int WAVES_N = 4;
  constexpr int WM = BM / 2;         // 32
  constexpr int WN = BN / WAVES_N;   // 64
  constexpr int TM = WM / 16;        // 2
  constexpr int TN = WN / 16;        // 4
  constexpr int ITER_B = (BN * BK) / (NT * 8);   // 4

  __shared__ __align__(16) f16 sA[BM * BK];
  __shared__ __align__(16) f16 sB[BN * BK];

  const int tid  = threadIdx.x;
  const int lane = tid & 63;
  const int wave = tid >> 6;
  const int wm   = wave / WAVES_N;
  const int wn   = wave % WAVES_N;
  const int m0   = blockIdx.x * BM;
  const int n0   = blockIdx.y * BN;
  const int quad = lane >> 4;
  const int l16  = lane & 15;

  uint32_t offA;
  {
    const int row = tid >> 3;
    const int q   = (tid & 7) ^ (row & 7);
    offA = (uint32_t)(((size_t)(m0 + row) * K + q * 8) * 4);
  }

  f32x4 acc[TM][TN];
#pragma unroll
  for (int i = 0; i < TM; ++i)
#pragma unroll
    for (int j = 0; j < TN; ++j)
      acc[i][j] = (f32x4){0.f, 0.f, 0.f, 0.f};

  float4 pa0, pa1;
  {
    const float4* p = (const float4*)((const char*)Aptr + offA);
    pa0 = p[0]; pa1 = p[1];
  }

  for (int kt = 0; kt < K; kt += BK) {
#pragma unroll
    for (int j = 0; j < ITER_B; ++j) {
      const int linear = j * NT + tid;
      const int row = linear >> 3;
      const int q   = (linear & 7) ^ (row & 7);
      async_cp16(BT + (size_t)(n0 + row) * K + kt + q * 8, &sB[linear * 8]);
    }
    {
      f16x8 o;
      o[0] = (f16)pa0.x; o[1] = (f16)pa0.y; o[2] = (f16)pa0.z; o[3] = (f16)pa0.w;
      o[4] = (f16)pa1.x; o[5] = (f16)pa1.y; o[6] = (f16)pa1.z; o[7] = (f16)pa1.w;
      *(f16x8*)&sA[(size_t)tid * 8] = o;
    }
    __syncthreads();   // barrier1

    if (kt + BK < K) {   // prefetch next A-regs; drains at barrier2
      const float4* p = (const float4*)((const char*)Aptr + (size_t)(kt + BK) * 4 + offA);
      pa0 = p[0]; pa1 = p[1];
    }

#pragma unroll
    for (int kk = 0; kk < 2; ++kk) {
      const int c = quad + kk * 4;
      f16x8 af[TM], bf[TN];
#pragma unroll
      for (int mi = 0; mi < TM; ++mi) {
        const int ml = wm * WM + mi * 16 + l16;
        af[mi] = *(const f16x8*)&sA[ml * 64 + ((c ^ (ml & 7)) * 8)];
      }
#pragma unroll
      for (int ni = 0; ni < TN; ++ni) {
        const int nl = wn * WN + ni * 16 + l16;
        bf[ni] = *(const f16x8*)&sB[nl * 64 + ((c ^ (nl & 7)) * 8)];
      }
#pragma unroll
      for (int mi = 0; mi < TM; ++mi)
#pragma unroll
        for (int ni = 0; ni < TN; ++ni)
          acc[mi][ni] = __builtin_amdgcn_mfma_f32_16x16x32_f16(
              af[mi], bf[ni], acc[mi][ni], 0, 0, 0);
    }
    __syncthreads();   // barrier2
  }

#pragma unroll
  for (int ni = 0; ni < TN; ++ni) {
    const int nc = n0 + wn * WN + ni * 16 + l16;
    const float bv = HAS_BIAS ? bias[nc] : 0.0f;
#pragma unroll
    for (int mi = 0; mi < TM; ++mi) {
#pragma unroll
      for (int r = 0; r < 4; ++r) {
        const int mr = m0 + wm * WM + mi * 16 + quad * 4 + r;
        float v = acc[mi][ni][r] + bv;
        if (RELU) v = fmaxf(v, 0.0f);
        C[(size_t)mr * N + nc] = (f16)v;
      }
    }
  }
}

// ---------------------------------------------------------------------------
// GCN GEMM (one layer): C = act(band(h) @ W + b). m97 geometry: BM=128,
// BN=128, BK=64, 256 thr / 4 waves (2Mx2N), wave 64x64 (TM=4, TN=4, acc=64).
// A staged RAW with 2 halo rows (sA[130][64]); exact tridiag blend at
// fragment read (3 ds_read_b128 + 2 pk-fma). 32 MFMA/wave/K-step.
// N = K = 512 fixed. Grid (M/128, 4) = 512 blocks = 2/CU. LDS 32.6KB.
// ---------------------------------------------------------------------------
template<bool RELU>
__global__ __launch_bounds__(256, 2) void gcn_gemm_kernel(
    const f16* __restrict__ hin, const f16* __restrict__ WT,
    f16* __restrict__ C, const float* __restrict__ bias, int M)
{
  constexpr int BM = 128, BN = 128, BK = 64;
  constexpr int NT = 256;
  constexpr int TM = 4, TN = 4;
  constexpr int S = 2048, H = 512;
  constexpr int AROWS = BM + 2;      // 130

  __shared__ __align__(16) f16 sA[AROWS * BK];   // 16.6 KB
  __shared__ __align__(16) f16 sB[BN * BK];      // 16 KB

  const int tid  = threadIdx.x;
  const int lane = tid & 63;
  const int wave = tid >> 6;         // 0..3
  const int wm   = wave >> 1;        // 0..1
  const int wn   = wave & 1;         // 0..1
  const int quad = lane >> 4;
  const int l16  = lane & 15;
  const int m0   = blockIdx.x * BM;
  const int n0   = blockIdx.y * BN;

  const float dM = 0.57735026919f;   // (3+1e-8)^-1/2
  const float dE = 0.70710678118f;   // (2+1e-8)^-1/2

  // per-lane tridiag coefs for the TM A-fragment rows
  f16 cf[TM][3];
#pragma unroll
  for (int mi = 0; mi < TM; ++mi) {
    const int grow = m0 + wm * 64 + mi * 16 + l16;
    const int s = grow & (S - 1);
    const float dsv = (s == 0 || s == S - 1) ? dE : dM;
    cf[mi][0] = (f16)((s > 0)     ? dsv * ((s - 1 == 0) ? dE : dM)     : 0.0f);
    cf[mi][1] = (f16)(dsv * dsv);
    cf[mi][2] = (f16)((s < S - 1) ? dsv * ((s + 1 == S - 1) ? dE : dM) : 0.0f);
  }

  f32x4 acc[TM][TN];
#pragma unroll
  for (int i = 0; i < TM; ++i)
#pragma unroll
    for (int j = 0; j < TN; ++j)
      acc[i][j] = (f32x4){0.f, 0.f, 0.f, 0.f};

  for (int kt = 0; kt < H; kt += BK) {
    // ---- B: 128x64 = 1024 chunks, 4 iters, gl_lds ----
#pragma unroll
    for (int j = 0; j < 4; ++j) {
      const int linear = j * NT + tid;
      const int row = linear >> 3;
      const int q   = (linear & 7) ^ (row & 7);
      async_cp16(WT + (size_t)(n0 + row) * H + kt + q * 8, &sB[linear * 8]);
    }
    // ---- A main rows 1..128 (global m0..m0+127): chunks 8..1031 = 4x256 ----
#pragma unroll
    for (int j = 0; j < 4; ++j) {
      const int chunk = j * NT + tid + 8;      // 8..1031
      const int row = chunk >> 3;              // 1..128
      const int q   = (chunk & 7) ^ (row & 7);
      async_cp16(hin + (size_t)(m0 + row - 1) * H + kt + q * 8, &sA[chunk * 8]);
    }
    // ---- halo rows 0 and 129 (16 chunks, reg path; coef=0 at seq edges) ----
    if (tid < 16) {
      const int hi = tid >> 3;
      const int ldsrow = hi ? (BM + 1) : 0;    // 0 or 129
      const int i = tid & 7;
      const int q = i ^ (ldsrow & 7);
      int g = m0 - 1 + ldsrow;
      g = g < 0 ? 0 : (g >= M ? M - 1 : g);
      f16x8 v = *(const f16x8*)(hin + (size_t)g * H + kt + q * 8);
      *(f16x8*)&sA[(size_t)(ldsrow * 8 + i) * 8] = v;
    }
    __syncthreads();   // barrier1: gl_lds + ds_write drained

    // ---- compute: 2 kk x 16 MFMA per wave ----
#pragma unroll
    for (int kk = 0; kk < 2; ++kk) {
      const int c = quad + kk * 4;
      f16x8 af[TM], bf[TN];
#pragma unroll
      for (int mi = 0; mi < TM; ++mi) {
        const int ldr = wm * 64 + mi * 16 + l16 + 1;   // 1..128
        f16x8 pv = *(const f16x8*)&sA[(ldr - 1) * 64 + ((c ^ ((ldr - 1) & 7)) * 8)];
        f16x8 sv = *(const f16x8*)&sA[(ldr    ) * 64 + ((c ^ ((ldr    ) & 7)) * 8)];
        f16x8 nv = *(const f16x8*)&sA[(ldr + 1) * 64 + ((c ^ ((ldr + 1) & 7)) * 8)];
        f16x8 r = pv * splat8(cf[mi][0]);
        r += sv * splat8(cf[mi][1]);
        r += nv * splat8(cf[mi][2]);
        af[mi] = r;
      }
#pragma unroll
      for (int ni = 0; ni < TN; ++ni) {
        const int nl = wn * 64 + ni * 16 + l16;
        bf[ni] = *(const f16x8*)&sB[nl * 64 + ((c ^ (nl & 7)) * 8)];
      }
#pragma unroll
      for (int mi = 0; mi < TM; ++mi)
#pragma unroll
        for (int ni = 0; ni < TN; ++ni)
          acc[mi][ni] = __builtin_amdgcn_mfma_f32_16x16x32_f16(
              af[mi], bf[ni], acc[mi][ni], 0, 0, 0);
    }
    __syncthreads();   // barrier2
  }

#pragma unroll
  for (int ni = 0; ni < TN; ++ni) {
    const int nc = n0 + wn * 64 + ni * 16 + l16;
    const float bv = bias[nc];
#pragma unroll
    for (int mi = 0; mi < TM; ++mi) {
#pragma unroll
      for (int r = 0; r < 4; ++r) {
        const int mr = m0 + wm * 64 + mi * 16 + quad * 4 + r;
        float v = acc[mi][ni][r] + bv;
        if (RELU) v = fmaxf(v, 0.0f);
        C[(size_t)mr * H + nc] = (f16)v;
      }
    }
  }
}

// ---------------------------------------------------------------------------
// Fused head, 32 rows/block (512 blocks): z1[32][256] LDS -> z2[32][128] LDS
// -> sigmoid dot. Total ~53.8KB -> 2 blocks/CU.
// ---------------------------------------------------------------------------
__global__ __launch_bounds__(256) void head_fused_kernel(
    const f16* __restrict__ h, const f16* __restrict__ S1T,
    const f16* __restrict__ S2T,
    const float* __restrict__ s1b, const float* __restrict__ s2b,
    const float* __restrict__ s3w, const float* __restrict__ s3b,
    float* __restrict__ out)
{
  __shared__ __align__(16) char smem[36864 + 32 * 264 * 2];
  f16* sA  = (f16*)smem;             // [32*64]   = 4KB
  f16* sB  = (f16*)(smem + 4096);    // [256*64]  = 32KB
  f16* zs  = (f16*)(smem + 36864);   // [32][264]
  f16* z2s = (f16*)smem;             // [32][136] = 8.5KB (reuses sA+sB head)
  f16* sB2 = (f16*)(smem + 8704);    // [128*64]  = 16KB

  const int tid  = threadIdx.x;
  const int lane = tid & 63;
  const int wave = tid >> 6;
  const int quad = lane >> 4;
  const int l16  = lane & 15;
  const int m0   = blockIdx.x * 32;

  // ---- GEMM1: z1[32][256] = relu(h[32x512] @ S1T^T + s1b); wave = 32x64 ----
  f32x4 acc[2][4];
#pragma unroll
  for (int i = 0; i < 2; ++i)
#pragma unroll
    for (int j = 0; j < 4; ++j) acc[i][j] = (f32x4){0.f, 0.f, 0.f, 0.f};

  for (int kt = 0; kt < 512; kt += 64) {
    __syncthreads();
    {   // A: 32x64 halfs = 256 chunks, 1 iter
      const int linear = tid;
      const int row = linear >> 3;
      const int q   = (linear & 7) ^ (row & 7);
      async_cp16(h + (size_t)(m0 + row) * 512 + kt + q * 8, &sA[linear * 8]);
    }
#pragma unroll
    for (int j = 0; j < 8; ++j) {   // B: 256x64 halfs = 2048 chunks
      const int linear = j * 256 + tid;
      const int row = linear >> 3;
      const int q   = (linear & 7) ^ (row & 7);
      async_cp16(S1T + (size_t)row * 512 + kt + q * 8, &sB[linear * 8]);
    }
    __syncthreads();
#pragma unroll
    for (int kk = 0; kk < 2; ++kk) {
      const int c = quad + kk * 4;
      f16x8 af[2], bf[4];
#pragma unroll
      for (int mi = 0; mi < 2; ++mi) {
        const int ml = mi * 16 + l16;
        af[mi] = *(const f16x8*)&sA[ml * 64 + ((c ^ (ml & 7)) * 8)];
      }
#pragma unroll
      for (int ni = 0; ni < 4; ++ni) {
        const int nl = wave * 64 + ni * 16 + l16;
        bf[ni] = *(const f16x8*)&sB[nl * 64 + ((c ^ (nl & 7)) * 8)];
      }
#pragma unroll
      for (int mi = 0; mi < 2; ++mi)
#pragma unroll
        for (int ni = 0; ni < 4; ++ni)
          acc[mi][ni] = __builtin_amdgcn_mfma_f32_16x16x32_f16(
              af[mi], bf[ni], acc[mi][ni], 0, 0, 0);
    }
  }
#pragma unroll
  for (int ni = 0; ni < 4; ++ni) {
    const int nc = wave * 64 + ni * 16 + l16;
    const float bv = s1b[nc];
#pragma unroll
    for (int mi = 0; mi < 2; ++mi)
#pragma unroll
      for (int r = 0; r < 4; ++r) {
        const int row = mi * 16 + quad * 4 + r;
        zs[row * 264 + nc] = (f16)fmaxf(acc[mi][ni][r] + bv, 0.0f);
      }
  }
  __syncthreads();

  // ---- GEMM2: z2[32][128] = relu(z1 @ S2T^T + s2b); wave = 32x32 ----
  f32x4 acc2[2][2];
#pragma unroll
  for (int i = 0; i < 2; ++i)
#pragma unroll
    for (int j = 0; j < 2; ++j) acc2[i][j] = (f32x4){0.f, 0.f, 0.f, 0.f};

  for (int kt2 = 0; kt2 < 4; ++kt2) {
    __syncthreads();
#pragma unroll
    for (int j = 0; j < 4; ++j) {   // B2: 128x64 halfs = 1024 chunks
      const int linear = j * 256 + tid;
      const int row = linear >> 3;
      const int q   = (linear & 7) ^ (row & 7);
      async_cp16(S2T + (size_t)row * 256 + kt2 * 64 + q * 8, &sB2[linear * 8]);
    }
    __syncthreads();
#pragma unroll
    for (int kk = 0; kk < 2; ++kk) {
      const int c = quad + kk * 4;
      f16x8 af[2], bf[2];
#pragma unroll
      for (int mi = 0; mi < 2; ++mi) {
        const int row = mi * 16 + l16;
        af[mi] = *(const f16x8*)&zs[row * 264 + (kt2 * 8 + c) * 8];
      }
#pragma unroll
      for (int ni = 0; ni < 2; ++ni) {
        const int nl = wave * 32 + ni * 16 + l16;
        bf[ni] = *(const f16x8*)&sB2[nl * 64 + ((c ^ (nl & 7)) * 8)];
      }
#pragma unroll
      for (int mi = 0; mi < 2; ++mi)
#pragma unroll
        for (int ni = 0; ni < 2; ++ni)
          acc2[mi][ni] = __builtin_amdgcn_mfma_f32_16x16x32_f16(
              af[mi], bf[ni], acc2[mi][ni], 0, 0, 0);
    }
  }
  __syncthreads();
#pragma unroll
  for (int ni = 0; ni < 2; ++ni) {
    const int nc = wave * 32 + ni * 16 + l16;
    const float bv = s2b[nc];
#pragma unroll
    for (int mi = 0; mi < 2; ++mi)
#pragma unroll
      for (int r = 0; r < 4; ++r) {
        const int row = mi * 16 + quad * 4 + r;
        z2s[row * 136 + nc] = (f16)fmaxf(acc2[mi][ni][r] + bv, 0.0f);
      }
  }
  __syncthreads();

  // ---- out[m] = sigmoid(dot(z2[m,:128], w) + b), 8 threads/row ----
  const int m  = tid >> 3;
  const int qd = tid & 7;
  float p = 0.f;
#pragma unroll
  for (int j = 0; j < 2; ++j) {
    f16x8 v = *(const f16x8*)&z2s[m * 136 + qd * 16 + j * 8];
#pragma unroll
    for (int e = 0; e < 8; ++e) p += (float)v[e] * s3w[qd * 16 + j * 8 + e];
  }
  p += __shfl_xor(p, 1);
  p += __shfl_xor(p, 2);
  p += __shfl_xor(p, 4);
  if (qd == 0) out[m0 + m] = 1.0f / (1.0f + expf(-(p + s3b[0])));
}

// ---------------------------------------------------------------------------
// Prep: 64x64 LDS tile-transposes of all weights (coalesced both sides).
// ---------------------------------------------------------------------------
__global__ __launch_bounds__(256) void prep_kernel(
    const float* __restrict__ Wp, f16* __restrict__ WpT,
    const float* __restrict__ gW, f16* __restrict__ GT,
    const float* __restrict__ s1W, f16* __restrict__ S1T,
    const float* __restrict__ s2W, f16* __restrict__ S2T)
{
  __shared__ f16 s[64 * 68];
  const int tid = threadIdx.x;
  int b = blockIdx.x;

  const float* W; f16* WT; int K, N, tile;
  if (b < 128)      { W = Wp;  WT = WpT; K = 1024; N = 512; tile = b; }
  else if (b < 320) { const int i = (b - 128) >> 6;
                      W = gW + (size_t)i * 262144; WT = GT + (size_t)i * 262144;
                      K = 512; N = 512; tile = (b - 128) & 63; }
  else if (b < 352) { W = s1W; WT = S1T; K = 512; N = 256; tile = b - 320; }
  else              { W = s2W; WT = S2T; K = 256; N = 128; tile = b - 352; }

  const int nt = tile % (N >> 6);
  const int kt = tile / (N >> 6);
#pragma unroll
  for (int it = 0; it < 16; ++it) {
    const int i  = it * 256 + tid;
    const int rk = i >> 6, rn = i & 63;
    s[rn * 68 + rk] = (f16)W[(size_t)(kt * 64 + rk) * N + nt * 64 + rn];
  }
  __syncthreads();
#pragma unroll
  for (int it = 0; it < 16; ++it) {
    const int i  = it * 256 + tid;
    const int rn = i >> 6, rk = i & 63;
    WT[(size_t)(nt * 64 + rn) * K + kt * 64 + rk] = s[rn * 68 + rk];
  }
}

// ---------------------------------------------------------------------------
extern "C" void kernel_launch(void* const* d_in, const int* in_sizes, int n_in,
                              void* d_out, int out_size, void* d_ws, size_t ws_size,
                              hipStream_t stream) {
  (void)in_sizes; (void)n_in; (void)out_size; (void)ws_size;
  const float* x   = (const float*)d_in[0];
  const float* Wp  = (const float*)d_in[1];
  const float* bp  = (const float*)d_in[2];
  const float* gW  = (const float*)d_in[3];
  const float* gb  = (const float*)d_in[4];
  const float* s1W = (const float*)d_in[5];
  const float* s1b = (const float*)d_in[6];
  const float* s2W = (const float*)d_in[7];
  const float* s2b = (const float*)d_in[8];
  const float* s3W = (const float*)d_in[9];
  const float* s3b = (const float*)d_in[10];
  float* out = (float*)d_out;

  constexpr int M = 16384;
  char* ws = (char*)d_ws;
  f16* hA  = (f16*)(ws + 0);            // 16384x512
  f16* hB  = (f16*)(ws + 16777216);     // 16384x512
  f16* WpT = (f16*)(ws + 33554432);     // [512,1024]
  f16* GT  = (f16*)(ws + 34603008);     // 3x[512,512]
  f16* S1T = (f16*)(ws + 36175872);     // [256,512]
  f16* S2T = (f16*)(ws + 36438016);     // [128,256]

  prep_kernel<<<360, 256, 0, stream>>>(Wp, WpT, gW, GT, s1W, S1T, s2W, S2T);

  // proj: hA = x @ Wp + bp  (R9-verified geometry)
  proj_gemm_kernel<64, 256, false, true>
      <<<dim3(M / 64, 2), 512, 0, stream>>>(x, WpT, hA, bp, M, 512, 1024);

  // GCN layers: 128x128 m97-geometry, exact band blend at fragment read
  gcn_gemm_kernel<true>
      <<<dim3(M / 128, 4), 256, 0, stream>>>(hA, GT, hB, gb, M);
  gcn_gemm_kernel<true>
      <<<dim3(M / 128, 4), 256, 0, stream>>>(hB, GT + 262144, hA, gb + 512, M);
  gcn_gemm_kernel<false>
      <<<dim3(M / 128, 4), 256, 0, stream>>>(hA, GT + 524288, hB, gb + 1024, M);

  head_fused_kernel<<<M / 32, 256, 0, stream>>>(hB, S1T, S2T, s1b, s2b, s3W, s3b, out);
}

// Round 13
// 198.638 us; speedup vs baseline: 2.9378x; 1.0048x over previous
//
#include <hip/hip_runtime.h>
#include <hip/hip_fp16.h>
#include <cstdint>
#include <cstddef>

// VideoSAGE: prep -> proj GEMM -> 3x GCN GEMM -> fused head. fp16 MFMA.
// R9/R10 (198us): 64x256 proj + halo-LDS band-blend GCN.
// R12-R15: 3-layer fusion abandoned (1024-thr VGPR cap 64 -> spills).
// R16 PM (199.6us): m97-geometry GCN (64 FLOP/B, 32 MFMA/wave/step) did NOT
//   help => amortization/intensity is not the wall. Arithmetic: GCN K-step
//   ~9000 cyc wall vs ~1300 cyc byte-service + ~300 cyc MFMA => ~7x exposed
//   latency; 2 blocks/CU can't cover the serialized stage->barrier round-trip
//   (m97 had ~3 blocks/CU).
// R17: T3 minimum-2-phase in proj + GCN: double-buffer LDS, STAGE(t+1) issued
//   BEFORE compute(t), deferred A ds-write after compute, ONE barrier/step.
//   Unlike R5 (dbuf capacity 3 < grid 4 -> 2nd scheduling round), dbuf
//   capacity now EXACTLY matches grid: proj 80KB, GCN 64.5KB -> 2 blocks/CU
//   = grid 512/256. Issue order: reg-loads first, gl_lds after, so the
//   pre-write vmcnt wait tolerates outstanding gl_lds.
// Falsifier: total unchanged => barrier vmcnt(0) drain irreducible at HIP
//   level -> next: raw s_barrier + counted vmcnt asm.

typedef _Float16 f16;
typedef _Float16 f16x8 __attribute__((ext_vector_type(8)));
typedef float    f32x4 __attribute__((ext_vector_type(4)));

__device__ __forceinline__ void async_cp16(const void* g, void* l) {
  __builtin_amdgcn_global_load_lds((const __attribute__((address_space(1))) void*)g,
                                   (__attribute__((address_space(3))) void*)l, 16, 0, 0);
}

__device__ __forceinline__ f16x8 splat8(f16 v) {
  f16x8 r;
#pragma unroll
  for (int e = 0; e < 8; ++e) r[e] = v;
  return r;
}

// ---------------------------------------------------------------------------
// Proj GEMM: C[M,N] = A(fp32)*BT^T + bias, cvt fp32->f16 in A staging.
// BM=64, BN=256, 512 thr (2x4 waves), grid (M/64, 2) = 512 = 2/CU.
// R17: 2-phase dbuf (LDS 80KB = exactly 2 blocks/CU).
// ---------------------------------------------------------------------------
template<int BM, int BN, bool RELU, bool HAS_BIAS>
__global__ __launch_bounds__(512, 2) void proj_gemm_kernel(
    const float* __restrict__ Aptr, const f16* __restrict__ BT,
    f16* __restrict__ C, const float* __restrict__ bias,
    int M, int N, int K)
{
  constexpr int BK = 64;
  constexpr int NT = 512;
  constexpr int WAVES_N = 4;
  constexpr int WM = BM / 2;         // 32
  constexpr int WN = BN / WAVES_N;   // 64
  constexpr int TM = WM / 16;        // 2
  constexpr int TN = WN / 16;        // 4
  constexpr int ITER_B = (BN * BK) / (NT * 8);   // 4

  __shared__ __align__(16) f16 sA[2][BM * BK];   // 2x8KB
  __shared__ __align__(16) f16 sB[2][BN * BK];   // 2x32KB

  const int tid  = threadIdx.x;
  const int lane = tid & 63;
  const int wave = tid >> 6;
  const int wm   = wave / WAVES_N;
  const int wn   = wave % WAVES_N;
  const int m0   = blockIdx.x * BM;
  const int n0   = blockIdx.y * BN;
  const int quad = lane >> 4;
  const int l16  = lane & 15;

  uint32_t offA;
  {
    const int row = tid >> 3;
    const int q   = (tid & 7) ^ (row & 7);
    offA = (uint32_t)(((size_t)(m0 + row) * K + q * 8) * 4);
  }

  f32x4 acc[TM][TN];
#pragma unroll
  for (int i = 0; i < TM; ++i)
#pragma unroll
    for (int j = 0; j < TN; ++j)
      acc[i][j] = (f32x4){0.f, 0.f, 0.f, 0.f};

  float4 pa0, pa1;

  auto stageB = [&](int kt, int b) {
#pragma unroll
    for (int j = 0; j < ITER_B; ++j) {
      const int linear = j * NT + tid;
      const int row = linear >> 3;
      const int q   = (linear & 7) ^ (row & 7);
      async_cp16(BT + (size_t)(n0 + row) * K + kt + q * 8, &sB[b][linear * 8]);
    }
  };
  auto writeA = [&](int b) {
    f16x8 o;
    o[0] = (f16)pa0.x; o[1] = (f16)pa0.y; o[2] = (f16)pa0.z; o[3] = (f16)pa0.w;
    o[4] = (f16)pa1.x; o[5] = (f16)pa1.y; o[6] = (f16)pa1.z; o[7] = (f16)pa1.w;
    *(f16x8*)&sA[b][(size_t)tid * 8] = o;
  };
  auto compute = [&](int b) {
#pragma unroll
    for (int kk = 0; kk < 2; ++kk) {
      const int c = quad + kk * 4;
      f16x8 af[TM], bf[TN];
#pragma unroll
      for (int mi = 0; mi < TM; ++mi) {
        const int ml = wm * WM + mi * 16 + l16;
        af[mi] = *(const f16x8*)&sA[b][ml * 64 + ((c ^ (ml & 7)) * 8)];
      }
#pragma unroll
      for (int ni = 0; ni < TN; ++ni) {
        const int nl = wn * WN + ni * 16 + l16;
        bf[ni] = *(const f16x8*)&sB[b][nl * 64 + ((c ^ (nl & 7)) * 8)];
      }
#pragma unroll
      for (int mi = 0; mi < TM; ++mi)
#pragma unroll
        for (int ni = 0; ni < TN; ++ni)
          acc[mi][ni] = __builtin_amdgcn_mfma_f32_16x16x32_f16(
              af[mi], bf[ni], acc[mi][ni], 0, 0, 0);
    }
  };

  // ---- prologue ----
  {
    const float4* p = (const float4*)((const char*)Aptr + offA);
    pa0 = p[0]; pa1 = p[1];
  }
  stageB(0, 0);
  writeA(0);
  __syncthreads();

  const int nt = K / BK;
  for (int t = 0; t < nt; ++t) {
    const int cur = t & 1;
    const bool pf = (t + 1 < nt);
    if (pf) {
      // reg-loads first (so the pre-write vmcnt wait tolerates gl_lds)
      const float4* p = (const float4*)((const char*)Aptr + (size_t)(t + 1) * BK * 4 + offA);
      pa0 = p[0]; pa1 = p[1];
      stageB((t + 1) * BK, cur ^ 1);
    }
    compute(cur);
    if (pf) writeA(cur ^ 1);   // vmcnt wait lands AFTER compute
    __syncthreads();           // one barrier per K-step
  }

#pragma unroll
  for (int ni = 0; ni < TN; ++ni) {
    const int nc = n0 + wn * WN + ni * 16 + l16;
    const float bv = HAS_BIAS ? bias[nc] : 0.0f;
#pragma unroll
    for (int mi = 0; mi < TM; ++mi) {
#pragma unroll
      for (int r = 0; r < 4; ++r) {
        const int mr = m0 + wm * WM + mi * 16 + quad * 4 + r;
        float v = acc[mi][ni][r] + bv;
        if (RELU) v = fmaxf(v, 0.0f);
        C[(size_t)mr * N + nc] = (f16)v;
      }
    }
  }
}

// ---------------------------------------------------------------------------
// GCN GEMM (one layer): C = act(band(h) @ W + b). 128x128, BK=64, 256 thr /
// 4 waves (2x2), wave 64x64 (TM=4,TN=4). A staged RAW + 2 halo rows; exact
// tridiag blend at fragment read. R17: 2-phase dbuf (LDS 64.5KB = 2/CU,
// grid (M/128,4)=512=2/CU).
// ---------------------------------------------------------------------------
template<bool RELU>
__global__ __launch_bounds__(256, 2) void gcn_gemm_kernel(
    const f16* __restrict__ hin, const f16* __restrict__ WT,
    f16* __restrict__ C, const float* __restrict__ bias, int M)
{
  constexpr int BM = 128, BN = 128, BK = 64;
  constexpr int NT = 256;
  constexpr int TM = 4, TN = 4;
  constexpr int S = 2048, H = 512;
  constexpr int AROWS = BM + 2;      // 130

  __shared__ __align__(16) f16 sA[2][AROWS * BK];   // 2x16.25KB
  __shared__ __align__(16) f16 sB[2][BN * BK];      // 2x16KB

  const int tid  = threadIdx.x;
  const int lane = tid & 63;
  const int wave = tid >> 6;         // 0..3
  const int wm   = wave >> 1;        // 0..1
  const int wn   = wave & 1;         // 0..1
  const int quad = lane >> 4;
  const int l16  = lane & 15;
  const int m0   = blockIdx.x * BM;
  const int n0   = blockIdx.y * BN;

  const float dM = 0.57735026919f;   // (3+1e-8)^-1/2
  const float dE = 0.70710678118f;   // (2+1e-8)^-1/2

  // per-lane tridiag coefs for the TM A-fragment rows
  f16 cf[TM][3];
#pragma unroll
  for (int mi = 0; mi < TM; ++mi) {
    const int grow = m0 + wm * 64 + mi * 16 + l16;
    const int s = grow & (S - 1);
    const float dsv = (s == 0 || s == S - 1) ? dE : dM;
    cf[mi][0] = (f16)((s > 0)     ? dsv * ((s - 1 == 0) ? dE : dM)     : 0.0f);
    cf[mi][1] = (f16)(dsv * dsv);
    cf[mi][2] = (f16)((s < S - 1) ? dsv * ((s + 1 == S - 1) ? dE : dM) : 0.0f);
  }

  // halo geometry (threads 0..15 handle rows 0 and 129)
  const int h_row = (tid >> 3) ? (BM + 1) : 0;
  const int h_i   = tid & 7;
  const int h_q   = h_i ^ (h_row & 7);
  int hg = m0 - 1 + h_row;
  hg = hg < 0 ? 0 : (hg >= M ? M - 1 : hg);
  f16x8 h_v;

  auto halo_load = [&](int kt) {
    if (tid < 16) h_v = *(const f16x8*)(hin + (size_t)hg * H + kt + h_q * 8);
  };
  auto halo_write = [&](int b) {
    if (tid < 16) *(f16x8*)&sA[b][(size_t)(h_row * 8 + h_i) * 8] = h_v;
  };
  auto stage_glds = [&](int kt, int b) {
#pragma unroll
    for (int j = 0; j < 4; ++j) {   // B: 128x64 = 1024 chunks
      const int linear = j * NT + tid;
      const int row = linear >> 3;
      const int q   = (linear & 7) ^ (row & 7);
      async_cp16(WT + (size_t)(n0 + row) * H + kt + q * 8, &sB[b][linear * 8]);
    }
#pragma unroll
    for (int j = 0; j < 4; ++j) {   // A main rows 1..128: chunks 8..1031
      const int chunk = j * NT + tid + 8;
      const int row = chunk >> 3;
      const int q   = (chunk & 7) ^ (row & 7);
      async_cp16(hin + (size_t)(m0 + row - 1) * H + kt + q * 8, &sA[b][chunk * 8]);
    }
  };

  f32x4 acc[TM][TN];
#pragma unroll
  for (int i = 0; i < TM; ++i)
#pragma unroll
    for (int j = 0; j < TN; ++j)
      acc[i][j] = (f32x4){0.f, 0.f, 0.f, 0.f};

  auto compute = [&](int b) {
#pragma unroll
    for (int kk = 0; kk < 2; ++kk) {
      const int c = quad + kk * 4;
      f16x8 af[TM], bf[TN];
#pragma unroll
      for (int mi = 0; mi < TM; ++mi) {
        const int ldr = wm * 64 + mi * 16 + l16 + 1;   // 1..128
        f16x8 pv = *(const f16x8*)&sA[b][(ldr - 1) * 64 + ((c ^ ((ldr - 1) & 7)) * 8)];
        f16x8 sv = *(const f16x8*)&sA[b][(ldr    ) * 64 + ((c ^ ((ldr    ) & 7)) * 8)];
        f16x8 nv = *(const f16x8*)&sA[b][(ldr + 1) * 64 + ((c ^ ((ldr + 1) & 7)) * 8)];
        f16x8 r = pv * splat8(cf[mi][0]);
        r += sv * splat8(cf[mi][1]);
        r += nv * splat8(cf[mi][2]);
        af[mi] = r;
      }
#pragma unroll
      for (int ni = 0; ni < TN; ++ni) {
        const int nl = wn * 64 + ni * 16 + l16;
        bf[ni] = *(const f16x8*)&sB[b][nl * 64 + ((c ^ (nl & 7)) * 8)];
      }
#pragma unroll
      for (int mi = 0; mi < TM; ++mi)
#pragma unroll
        for (int ni = 0; ni < TN; ++ni)
          acc[mi][ni] = __builtin_amdgcn_mfma_f32_16x16x32_f16(
              af[mi], bf[ni], acc[mi][ni], 0, 0, 0);
    }
  };

  // ---- prologue: stage tile 0 into buffer 0 ----
  halo_load(0);
  stage_glds(0, 0);
  halo_write(0);
  __syncthreads();

  constexpr int NTILES = H / BK;   // 8
  for (int t = 0; t < NTILES; ++t) {
    const int cur = t & 1;
    const bool pf = (t + 1 < NTILES);
    if (pf) {
      halo_load((t + 1) * BK);               // reg-load first
      stage_glds((t + 1) * BK, cur ^ 1);     // gl_lds in flight under compute
    }
    compute(cur);
    if (pf) halo_write(cur ^ 1);             // vmcnt wait after compute
    __syncthreads();                         // one barrier per K-step
  }

#pragma unroll
  for (int ni = 0; ni < TN; ++ni) {
    const int nc = n0 + wn * 64 + ni * 16 + l16;
    const float bv = bias[nc];
#pragma unroll
    for (int mi = 0; mi < TM; ++mi) {
#pragma unroll
      for (int r = 0; r < 4; ++r) {
        const int mr = m0 + wm * 64 + mi * 16 + quad * 4 + r;
        float v = acc[mi][ni][r] + bv;
        if (RELU) v = fmaxf(v, 0.0f);
        C[(size_t)mr * H + nc] = (f16)v;
      }
    }
  }
}

// ---------------------------------------------------------------------------
// Fused head, 32 rows/block (512 blocks): z1[32][256] LDS -> z2[32][128] LDS
// -> sigmoid dot. Total ~53.8KB -> 2 blocks/CU.
// ---------------------------------------------------------------------------
__global__ __launch_bounds__(256) void head_fused_kernel(
    const f16* __restrict__ h, const f16* __restrict__ S1T,
    const f16* __restrict__ S2T,
    const float* __restrict__ s1b, const float* __restrict__ s2b,
    const float* __restrict__ s3w, const float* __restrict__ s3b,
    float* __restrict__ out)
{
  __shared__ __align__(16) char smem[36864 + 32 * 264 * 2];
  f16* sA  = (f16*)smem;             // [32*64]   = 4KB
  f16* sB  = (f16*)(smem + 4096);    // [256*64]  = 32KB
  f16* zs  = (f16*)(smem + 36864);   // [32][264]
  f16* z2s = (f16*)smem;             // [32][136] = 8.5KB (reuses sA+sB head)
  f16* sB2 = (f16*)(smem + 8704);    // [128*64]  = 16KB

  const int tid  = threadIdx.x;
  const int lane = tid & 63;
  const int wave = tid >> 6;
  const int quad = lane >> 4;
  const int l16  = lane & 15;
  const int m0   = blockIdx.x * 32;

  // ---- GEMM1: z1[32][256] = relu(h[32x512] @ S1T^T + s1b); wave = 32x64 ----
  f32x4 acc[2][4];
#pragma unroll
  for (int i = 0; i < 2; ++i)
#pragma unroll
    for (int j = 0; j < 4; ++j) acc[i][j] = (f32x4){0.f, 0.f, 0.f, 0.f};

  for (int kt = 0; kt < 512; kt += 64) {
    __syncthreads();
    {   // A: 32x64 halfs = 256 chunks, 1 iter
      const int linear = tid;
      const int row = linear >> 3;
      const int q   = (linear & 7) ^ (row & 7);
      async_cp16(h + (size_t)(m0 + row) * 512 + kt + q * 8, &sA[linear * 8]);
    }
#pragma unroll
    for (int j = 0; j < 8; ++j) {   // B: 256x64 halfs = 2048 chunks
      const int linear = j * 256 + tid;
      const int row = linear >> 3;
      const int q   = (linear & 7) ^ (row & 7);
      async_cp16(S1T + (size_t)row * 512 + kt + q * 8, &sB[linear * 8]);
    }
    __syncthreads();
#pragma unroll
    for (int kk = 0; kk < 2; ++kk) {
      const int c = quad + kk * 4;
      f16x8 af[2], bf[4];
#pragma unroll
      for (int mi = 0; mi < 2; ++mi) {
        const int ml = mi * 16 + l16;
        af[mi] = *(const f16x8*)&sA[ml * 64 + ((c ^ (ml & 7)) * 8)];
      }
#pragma unroll
      for (int ni = 0; ni < 4; ++ni) {
        const int nl = wave * 64 + ni * 16 + l16;
        bf[ni] = *(const f16x8*)&sB[nl * 64 + ((c ^ (nl & 7)) * 8)];
      }
#pragma unroll
      for (int mi = 0; mi < 2; ++mi)
#pragma unroll
        for (int ni = 0; ni < 4; ++ni)
          acc[mi][ni] = __builtin_amdgcn_mfma_f32_16x16x32_f16(
              af[mi], bf[ni], acc[mi][ni], 0, 0, 0);
    }
  }
#pragma unroll
  for (int ni = 0; ni < 4; ++ni) {
    const int nc = wave * 64 + ni * 16 + l16;
    const float bv = s1b[nc];
#pragma unroll
    for (int mi = 0; mi < 2; ++mi)
#pragma unroll
      for (int r = 0; r < 4; ++r) {
        const int row = mi * 16 + quad * 4 + r;
        zs[row * 264 + nc] = (f16)fmaxf(acc[mi][ni][r] + bv, 0.0f);
      }
  }
  __syncthreads();

  // ---- GEMM2: z2[32][128] = relu(z1 @ S2T^T + s2b); wave = 32x32 ----
  f32x4 acc2[2][2];
#pragma unroll
  for (int i = 0; i < 2; ++i)
#pragma unroll
    for (int j = 0; j < 2; ++j) acc2[i][j] = (f32x4){0.f, 0.f, 0.f, 0.f};

  for (int kt2 = 0; kt2 < 4; ++kt2) {
    __syncthreads();
#pragma unroll
    for (int j = 0; j < 4; ++j) {   // B2: 128x64 halfs = 1024 chunks
      const int linear = j * 256 + tid;
      const int row = linear >> 3;
      const int q   = (linear & 7) ^ (row & 7);
      async_cp16(S2T + (size_t)row * 256 + kt2 * 64 + q * 8, &sB2[linear * 8]);
    }
    __syncthreads();
#pragma unroll
    for (int kk = 0; kk < 2; ++kk) {
      const int c = quad + kk * 4;
      f16x8 af[2], bf[2];
#pragma unroll
      for (int mi = 0; mi < 2; ++mi) {
        const int row = mi * 16 + l16;
        af[mi] = *(const f16x8*)&zs[row * 264 + (kt2 * 8 + c) * 8];
      }
#pragma unroll
      for (int ni = 0; ni < 2; ++ni) {
        const int nl = wave * 32 + ni * 16 + l16;
        bf[ni] = *(const f16x8*)&sB2[nl * 64 + ((c ^ (nl & 7)) * 8)];
      }
#pragma unroll
      for (int mi = 0; mi < 2; ++mi)
#pragma unroll
        for (int ni = 0; ni < 2; ++ni)
          acc2[mi][ni] = __builtin_amdgcn_mfma_f32_16x16x32_f16(
              af[mi], bf[ni], acc2[mi][ni], 0, 0, 0);
    }
  }
  __syncthreads();
#pragma unroll
  for (int ni = 0; ni < 2; ++ni) {
    const int nc = wave * 32 + ni * 16 + l16;
    const float bv = s2b[nc];
#pragma unroll
    for (int mi = 0; mi < 2; ++mi)
#pragma unroll
      for (int r = 0; r < 4; ++r) {
        const int row = mi * 16 + quad * 4 + r;
        z2s[row * 136 + nc] = (f16)fmaxf(acc2[mi][ni][r] + bv, 0.0f);
      }
  }
  __syncthreads();

  // ---- out[m] = sigmoid(dot(z2[m,:128], w) + b), 8 threads/row ----
  const int m  = tid >> 3;
  const int qd = tid & 7;
  float p = 0.f;
#pragma unroll
  for (int j = 0; j < 2; ++j) {
    f16x8 v = *(const f16x8*)&z2s[m * 136 + qd * 16 + j * 8];
#pragma unroll
    for (int e = 0; e < 8; ++e) p += (float)v[e] * s3w[qd * 16 + j * 8 + e];
  }
  p += __shfl_xor(p, 1);
  p += __shfl_xor(p, 2);
  p += __shfl_xor(p, 4);
  if (qd == 0) out[m0 + m] = 1.0f / (1.0f + expf(-(p + s3b[0])));
}

// ---------------------------------------------------------------------------
// Prep: 64x64 LDS tile-transposes of all weights (coalesced both sides).
// ---------------------------------------------------------------------------
__global__ __launch_bounds__(256) void prep_kernel(
    const float* __restrict__ Wp, f16* __restrict__ WpT,
    const float* __restrict__ gW, f16* __restrict__ GT,
    const float* __restrict__ s1W, f16* __restrict__ S1T,
    const float* __restrict__ s2W, f16* __restrict__ S2T)
{
  __shared__ f16 s[64 * 68];
  const int tid = threadIdx.x;
  int b = blockIdx.x;

  const float* W; f16* WT; int K, N, tile;
  if (b < 128)      { W = Wp;  WT = WpT; K = 1024; N = 512; tile = b; }
  else if (b < 320) { const int i = (b - 128) >> 6;
                      W = gW + (size_t)i * 262144; WT = GT + (size_t)i * 262144;
                      K = 512; N = 512; tile = (b - 128) & 63; }
  else if (b < 352) { W = s1W; WT = S1T; K = 512; N = 256; tile = b - 320; }
  else              { W = s2W; WT = S2T; K = 256; N = 128; tile = b - 352; }

  const int nt = tile % (N >> 6);
  const int kt = tile / (N >> 6);
#pragma unroll
  for (int it = 0; it < 16; ++it) {
    const int i  = it * 256 + tid;
    const int rk = i >> 6, rn = i & 63;
    s[rn * 68 + rk] = (f16)W[(size_t)(kt * 64 + rk) * N + nt * 64 + rn];
  }
  __syncthreads();
#pragma unroll
  for (int it = 0; it < 16; ++it) {
    const int i  = it * 256 + tid;
    const int rn = i >> 6, rk = i & 63;
    WT[(size_t)(nt * 64 + rn) * K + kt * 64 + rk] = s[rn * 68 + rk];
  }
}

// ---------------------------------------------------------------------------
extern "C" void kernel_launch(void* const* d_in, const int* in_sizes, int n_in,
                              void* d_out, int out_size, void* d_ws, size_t ws_size,
                              hipStream_t stream) {
  (void)in_sizes; (void)n_in; (void)out_size; (void)ws_size;
  const float* x   = (const float*)d_in[0];
  const float* Wp  = (const float*)d_in[1];
  const float* bp  = (const float*)d_in[2];
  const float* gW  = (const float*)d_in[3];
  const float* gb  = (const float*)d_in[4];
  const float* s1W = (const float*)d_in[5];
  const float* s1b = (const float*)d_in[6];
  const float* s2W = (const float*)d_in[7];
  const float* s2b = (const float*)d_in[8];
  const float* s3W = (const float*)d_in[9];
  const float* s3b = (const float*)d_in[10];
  float* out = (float*)d_out;

  constexpr int M = 16384;
  char* ws = (char*)d_ws;
  f16* hA  = (f16*)(ws + 0);            // 16384x512
  f16* hB  = (f16*)(ws + 16777216);     // 16384x512
  f16* WpT = (f16*)(ws + 33554432);     // [512,1024]
  f16* GT  = (f16*)(ws + 34603008);     // 3x[512,512]
  f16* S1T = (f16*)(ws + 36175872);     // [256,512]
  f16* S2T = (f16*)(ws + 36438016);     // [128,256]

  prep_kernel<<<360, 256, 0, stream>>>(Wp, WpT, gW, GT, s1W, S1T, s2W, S2T);

  // proj: hA = x @ Wp + bp  (2-phase dbuf)
  proj_gemm_kernel<64, 256, false, true>
      <<<dim3(M / 64, 2), 512, 0, stream>>>(x, WpT, hA, bp, M, 512, 1024);

  // GCN layers: 128x128, exact band blend, 2-phase dbuf
  gcn_gemm_kernel<true>
      <<<dim3(M / 128, 4), 256, 0, stream>>>(hA, GT, hB, gb, M);
  gcn_gemm_kernel<true>
      <<<dim3(M / 128, 4), 256, 0, stream>>>(hB, GT + 262144, hA, gb + 512, M);
  gcn_gemm_kernel<false>
      <<<dim3(M / 128, 4), 256, 0, stream>>>(hA, GT + 524288, hB, gb + 1024, M);

  head_fused_kernel<<<M / 32, 256, 0, stream>>>(hB, S1T, S2T, s1b, s2b, s3W, s3b, out);
}

// Round 15
// 198.607 us; speedup vs baseline: 2.9383x; 1.0002x over previous
//
#include <hip/hip_runtime.h>
#include <hip/hip_fp16.h>
#include <cstdint>
#include <cstddef>

// VideoSAGE: prep -> proj GEMM -> 3x GCN GEMM -> fused head. fp16 MFMA.
// R9/R10 (198us): 64x256 proj + halo-LDS band-blend GCN.
// R16 PM (199.6): m97 geometry null -> amortization not the wall.
// R17 PM (198.6): 2-phase dbuf: proj IMPROVED 43.8->~25us, but GCN regressed
//   to 48.5us with 24MB scratch writes (WRITE 41 vs 17MB) -- reg-path halo
//   (divergent h_v live across compute) + dbuf lambdas spilled; plus the
//   __syncthreads vmcnt(0) drain serializes each step.
// R18: GCN rebuilt: (a) ALL-gl_lds staging -- 130 rows as 1040 chunks =
//   4x256/thread + 16 halo chunks issued redundantly by lane<16 of EVERY
//   wave (same bytes, benign; uniform 9 vmem/wave/stage). No reg-path, no
//   ds_write, no divergent liveness. (b) counted vmcnt: stage(t+1) ->
//   s_waitcnt vmcnt(9) (t's loads drained, t+1's stay in flight ACROSS the
//   barrier) -> raw s_barrier -> compute(t) -> raw s_barrier. Offsets
//   precomputed (uint32 elems). Proj/head/prep = R17 exactly.
// R19: resubmit of R18 unchanged -- round 14 bench was the session's third
//   "container failed twice" infra error (rounds 5, 9 benched fine on
//   resubmit). Audit: uniform barriers/trip counts, wave-uniform vmcnt=9
//   (lane<16 true in every wave), no ds_write/lgkm hazard, clamped bounds.
// Falsifiers: GCN dur 12-18us, WRITE ~17MB, VGPR 110-140; if GCN >=40 with
//   clean WRITE -> wall is elsewhere; need full per-kernel breakdown next.

typedef _Float16 f16;
typedef _Float16 f16x8 __attribute__((ext_vector_type(8)));
typedef float    f32x4 __attribute__((ext_vector_type(4)));

__device__ __forceinline__ void async_cp16(const void* g, void* l) {
  __builtin_amdgcn_global_load_lds((const __attribute__((address_space(1))) void*)g,
                                   (__attribute__((address_space(3))) void*)l, 16, 0, 0);
}

__device__ __forceinline__ f16x8 splat8(f16 v) {
  f16x8 r;
#pragma unroll
  for (int e = 0; e < 8; ++e) r[e] = v;
  return r;
}

// ---------------------------------------------------------------------------
// Proj GEMM: C[M,N] = A(fp32)*BT^T + bias, cvt fp32->f16 in A staging.
// BM=64, BN=256, 512 thr (2x4 waves), grid (M/64, 2) = 512 = 2/CU.
// R17 2-phase dbuf (LDS 80KB = exactly 2 blocks/CU) -- measured ~25us, keep.
// ---------------------------------------------------------------------------
template<int BM, int BN, bool RELU, bool HAS_BIAS>
__global__ __launch_bounds__(512, 2) void proj_gemm_kernel(
    const float* __restrict__ Aptr, const f16* __restrict__ BT,
    f16* __restrict__ C, const float* __restrict__ bias,
    int M, int N, int K)
{
  constexpr int BK = 64;
  constexpr int NT = 512;
  constexpr int WAVES_N = 4;
  constexpr int WM = BM / 2;         // 32
  constexpr int WN = BN / WAVES_N;   // 64
  constexpr int TM = WM / 16;        // 2
  constexpr int TN = WN / 16;        // 4
  constexpr int ITER_B = (BN * BK) / (NT * 8);   // 4

  __shared__ __align__(16) f16 sA[2][BM * BK];   // 2x8KB
  __shared__ __align__(16) f16 sB[2][BN * BK];   // 2x32KB

  const int tid  = threadIdx.x;
  const int lane = tid & 63;
  const int wave = tid >> 6;
  const int wm   = wave / WAVES_N;
  const int wn   = wave % WAVES_N;
  const int m0   = blockIdx.x * BM;
  const int n0   = blockIdx.y * BN;
  const int quad = lane >> 4;
  const int l16  = lane & 15;

  uint32_t offA;
  {
    const int row = tid >> 3;
    const int q   = (tid & 7) ^ (row & 7);
    offA = (uint32_t)(((size_t)(m0 + row) * K + q * 8) * 4);
  }

  f32x4 acc[TM][TN];
#pragma unroll
  for (int i = 0; i < TM; ++i)
#pragma unroll
    for (int j = 0; j < TN; ++j)
      acc[i][j] = (f32x4){0.f, 0.f, 0.f, 0.f};

  float4 pa0, pa1;

  auto stageB = [&](int kt, int b) {
#pragma unroll
    for (int j = 0; j < ITER_B; ++j) {
      const int linear = j * NT + tid;
      const int row = linear >> 3;
      const int q   = (linear & 7) ^ (row & 7);
      async_cp16(BT + (size_t)(n0 + row) * K + kt + q * 8, &sB[b][linear * 8]);
    }
  };
  auto writeA = [&](int b) {
    f16x8 o;
    o[0] = (f16)pa0.x; o[1] = (f16)pa0.y; o[2] = (f16)pa0.z; o[3] = (f16)pa0.w;
    o[4] = (f16)pa1.x; o[5] = (f16)pa1.y; o[6] = (f16)pa1.z; o[7] = (f16)pa1.w;
    *(f16x8*)&sA[b][(size_t)tid * 8] = o;
  };
  auto compute = [&](int b) {
#pragma unroll
    for (int kk = 0; kk < 2; ++kk) {
      const int c = quad + kk * 4;
      f16x8 af[TM], bf[TN];
#pragma unroll
      for (int mi = 0; mi < TM; ++mi) {
        const int ml = wm * WM + mi * 16 + l16;
        af[mi] = *(const f16x8*)&sA[b][ml * 64 + ((c ^ (ml & 7)) * 8)];
      }
#pragma unroll
      for (int ni = 0; ni < TN; ++ni) {
        const int nl = wn * WN + ni * 16 + l16;
        bf[ni] = *(const f16x8*)&sB[b][nl * 64 + ((c ^ (nl & 7)) * 8)];
      }
#pragma unroll
      for (int mi = 0; mi < TM; ++mi)
#pragma unroll
        for (int ni = 0; ni < TN; ++ni)
          acc[mi][ni] = __builtin_amdgcn_mfma_f32_16x16x32_f16(
              af[mi], bf[ni], acc[mi][ni], 0, 0, 0);
    }
  };

  // ---- prologue ----
  {
    const float4* p = (const float4*)((const char*)Aptr + offA);
    pa0 = p[0]; pa1 = p[1];
  }
  stageB(0, 0);
  writeA(0);
  __syncthreads();

  const int nt = K / BK;
  for (int t = 0; t < nt; ++t) {
    const int cur = t & 1;
    const bool pf = (t + 1 < nt);
    if (pf) {
      // reg-loads first (so the pre-write vmcnt wait tolerates gl_lds)
      const float4* p = (const float4*)((const char*)Aptr + (size_t)(t + 1) * BK * 4 + offA);
      pa0 = p[0]; pa1 = p[1];
      stageB((t + 1) * BK, cur ^ 1);
    }
    compute(cur);
    if (pf) writeA(cur ^ 1);   // vmcnt wait lands AFTER compute
    __syncthreads();           // one barrier per K-step
  }

#pragma unroll
  for (int ni = 0; ni < TN; ++ni) {
    const int nc = n0 + wn * WN + ni * 16 + l16;
    const float bv = HAS_BIAS ? bias[nc] : 0.0f;
#pragma unroll
    for (int mi = 0; mi < TM; ++mi) {
#pragma unroll
      for (int r = 0; r < 4; ++r) {
        const int mr = m0 + wm * WM + mi * 16 + quad * 4 + r;
        float v = acc[mi][ni][r] + bv;
        if (RELU) v = fmaxf(v, 0.0f);
        C[(size_t)mr * N + nc] = (f16)v;
      }
    }
  }
}

// ---------------------------------------------------------------------------
// GCN GEMM (one layer): C = act(band(h) @ W + b). 128x128, BK=64, 256 thr /
// 4 waves (2x2), wave 64x64 (TM=4,TN=4). R18: all-gl_lds staging of 130 rows
// (ldsrow r <-> global m0-1+r), counted-vmcnt 2-phase dbuf, raw barriers.
// 9 vmem/stage/wave uniform (4 B + 4 A + 1 redundant halo by lane<16 of
// every wave). LDS 64.5KB -> 2 blocks/CU = grid (M/128,4)=512.
// ---------------------------------------------------------------------------
template<bool RELU>
__global__ __launch_bounds__(256, 2) void gcn_gemm_kernel(
    const f16* __restrict__ hin, const f16* __restrict__ WT,
    f16* __restrict__ C, const float* __restrict__ bias, int M)
{
  constexpr int BM = 128, BN = 128, BK = 64;
  constexpr int NT = 256;
  constexpr int TM = 4, TN = 4;
  constexpr int S = 2048, H = 512;
  constexpr int AROWS = BM + 2;      // 130

  __shared__ __align__(16) f16 sA[2][AROWS * BK];   // 2x16.25KB
  __shared__ __align__(16) f16 sB[2][BN * BK];      // 2x16KB

  const int tid  = threadIdx.x;
  const int lane = tid & 63;
  const int wave = tid >> 6;         // 0..3
  const int wm   = wave >> 1;        // 0..1
  const int wn   = wave & 1;         // 0..1
  const int quad = lane >> 4;
  const int l16  = lane & 15;
  const int m0   = blockIdx.x * BM;
  const int n0   = blockIdx.y * BN;

  const float dM = 0.57735026919f;   // (3+1e-8)^-1/2
  const float dE = 0.70710678118f;   // (2+1e-8)^-1/2

  // per-lane tridiag coefs for the TM A-fragment rows
  f16 cf[TM][3];
#pragma unroll
  for (int mi = 0; mi < TM; ++mi) {
    const int grow = m0 + wm * 64 + mi * 16 + l16;
    const int s = grow & (S - 1);
    const float dsv = (s == 0 || s == S - 1) ? dE : dM;
    cf[mi][0] = (f16)((s > 0)     ? dsv * ((s - 1 == 0) ? dE : dM)     : 0.0f);
    cf[mi][1] = (f16)(dsv * dsv);
    cf[mi][2] = (f16)((s < S - 1) ? dsv * ((s + 1 == S - 1) ? dE : dM) : 0.0f);
  }

  // ---- precomputed element offsets (uint32; buffers < 2^32 elems) ----
  uint32_t offB[4], offA[4], offH;
#pragma unroll
  for (int j = 0; j < 4; ++j) {
    const int linear = j * NT + tid;
    const int row = linear >> 3;
    const int q   = (linear & 7) ^ (row & 7);
    offB[j] = (uint32_t)((size_t)(n0 + row) * H + q * 8);
  }
#pragma unroll
  for (int j = 0; j < 4; ++j) {
    const int c = j * NT + tid;          // chunks 0..1023 -> ldsrows 0..127
    const int r = c >> 3;
    const int q = (c & 7) ^ (r & 7);
    int g = m0 - 1 + r;
    g = g < 0 ? 0 : (g >= M ? M - 1 : g);
    offA[j] = (uint32_t)((size_t)g * H + q * 8);
  }
  {
    const int c = 1024 + (lane & 15);    // ldsrows 128,129 (lanes<16 only)
    const int r = c >> 3;
    const int q = (c & 7) ^ (r & 7);
    int g = m0 - 1 + r;
    g = g < 0 ? 0 : (g >= M ? M - 1 : g);
    offH = (uint32_t)((size_t)g * H + q * 8);
  }

  auto stage = [&](int kt, int b) {
#pragma unroll
    for (int j = 0; j < 4; ++j)
      async_cp16(WT + (size_t)offB[j] + kt, &sB[b][(j * NT + tid) * 8]);
#pragma unroll
    for (int j = 0; j < 4; ++j)
      async_cp16(hin + (size_t)offA[j] + kt, &sA[b][(j * NT + tid) * 8]);
    if (lane < 16)   // all 4 waves issue (same bytes -> benign; count uniform)
      async_cp16(hin + (size_t)offH + kt, &sA[b][(1024 + lane) * 8]);
  };

  f32x4 acc[TM][TN];
#pragma unroll
  for (int i = 0; i < TM; ++i)
#pragma unroll
    for (int j = 0; j < TN; ++j)
      acc[i][j] = (f32x4){0.f, 0.f, 0.f, 0.f};

  auto compute = [&](int b) {
#pragma unroll
    for (int kk = 0; kk < 2; ++kk) {
      const int c = quad + kk * 4;
      f16x8 af[TM], bf[TN];
#pragma unroll
      for (int mi = 0; mi < TM; ++mi) {
        const int ldr = wm * 64 + mi * 16 + l16 + 1;   // 1..128
        f16x8 pv = *(const f16x8*)&sA[b][(ldr - 1) * 64 + ((c ^ ((ldr - 1) & 7)) * 8)];
        f16x8 sv = *(const f16x8*)&sA[b][(ldr    ) * 64 + ((c ^ ((ldr    ) & 7)) * 8)];
        f16x8 nv = *(const f16x8*)&sA[b][(ldr + 1) * 64 + ((c ^ ((ldr + 1) & 7)) * 8)];
        f16x8 r = pv * splat8(cf[mi][0]);
        r += sv * splat8(cf[mi][1]);
        r += nv * splat8(cf[mi][2]);
        af[mi] = r;
      }
#pragma unroll
      for (int ni = 0; ni < TN; ++ni) {
        const int nl = wn * 64 + ni * 16 + l16;
        bf[ni] = *(const f16x8*)&sB[b][nl * 64 + ((c ^ (nl & 7)) * 8)];
      }
#pragma unroll
      for (int mi = 0; mi < TM; ++mi)
#pragma unroll
        for (int ni = 0; ni < TN; ++ni)
          acc[mi][ni] = __builtin_amdgcn_mfma_f32_16x16x32_f16(
              af[mi], bf[ni], acc[mi][ni], 0, 0, 0);
    }
  };

  // ---- counted-vmcnt 2-phase loop ----
  stage(0, 0);                           // 9 outstanding
  constexpr int NTILES = H / BK;         // 8
  for (int t = 0; t < NTILES; ++t) {
    const int cur = t & 1;
    if (t + 1 < NTILES) {
      stage((t + 1) * BK, cur ^ 1);      // 18 outstanding
      asm volatile("s_waitcnt vmcnt(9)" ::: "memory");   // drain t, keep t+1
    } else {
      asm volatile("s_waitcnt vmcnt(0)" ::: "memory");
    }
    asm volatile("s_barrier" ::: "memory");    // all waves: tile t ready
    __builtin_amdgcn_sched_barrier(0);
    compute(cur);
    asm volatile("s_barrier" ::: "memory");    // tile t fully consumed
  }

#pragma unroll
  for (int ni = 0; ni < TN; ++ni) {
    const int nc = n0 + wn * 64 + ni * 16 + l16;
    const float bv = bias[nc];
#pragma unroll
    for (int mi = 0; mi < TM; ++mi) {
#pragma unroll
      for (int r = 0; r < 4; ++r) {
        const int mr = m0 + wm * 64 + mi * 16 + quad * 4 + r;
        float v = acc[mi][ni][r] + bv;
        if (RELU) v = fmaxf(v, 0.0f);
        C[(size_t)mr * H + nc] = (f16)v;
      }
    }
  }
}

// ---------------------------------------------------------------------------
// Fused head, 32 rows/block (512 blocks): z1[32][256] LDS -> z2[32][128] LDS
// -> sigmoid dot. Total ~53.8KB -> 2 blocks/CU.
// ---------------------------------------------------------------------------
__global__ __launch_bounds__(256) void head_fused_kernel(
    const f16* __restrict__ h, const f16* __restrict__ S1T,
    const f16* __restrict__ S2T,
    const float* __restrict__ s1b, const float* __restrict__ s2b,
    const float* __restrict__ s3w, const float* __restrict__ s3b,
    float* __restrict__ out)
{
  __shared__ __align__(16) char smem[36864 + 32 * 264 * 2];
  f16* sA  = (f16*)smem;             // [32*64]   = 4KB
  f16* sB  = (f16*)(smem + 4096);    // [256*64]  = 32KB
  f16* zs  = (f16*)(smem + 36864);   // [32][264]
  f16* z2s = (f16*)smem;             // [32][136] = 8.5KB (reuses sA+sB head)
  f16* sB2 = (f16*)(smem + 8704);    // [128*64]  = 16KB

  const int tid  = threadIdx.x;
  const int lane = tid & 63;
  const int wave = tid >> 6;
  const int quad = lane >> 4;
  const int l16  = lane & 15;
  const int m0   = blockIdx.x * 32;

  // ---- GEMM1: z1[32][256] = relu(h[32x512] @ S1T^T + s1b); wave = 32x64 ----
  f32x4 acc[2][4];
#pragma unroll
  for (int i = 0; i < 2; ++i)
#pragma unroll
    for (int j = 0; j < 4; ++j) acc[i][j] = (f32x4){0.f, 0.f, 0.f, 0.f};

  for (int kt = 0; kt < 512; kt += 64) {
    __syncthreads();
    {   // A: 32x64 halfs = 256 chunks, 1 iter
      const int linear = tid;
      const int row = linear >> 3;
      const int q   = (linear & 7) ^ (row & 7);
      async_cp16(h + (size_t)(m0 + row) * 512 + kt + q * 8, &sA[linear * 8]);
    }
#pragma unroll
    for (int j = 0; j < 8; ++j) {   // B: 256x64 halfs = 2048 chunks
      const int linear = j * 256 + tid;
      const int row = linear >> 3;
      const int q   = (linear & 7) ^ (row & 7);
      async_cp16(S1T + (size_t)row * 512 + kt + q * 8, &sB[linear * 8]);
    }
    __syncthreads();
#pragma unroll
    for (int kk = 0; kk < 2; ++kk) {
      const int c = quad + kk * 4;
      f16x8 af[2], bf[4];
#pragma unroll
      for (int mi = 0; mi < 2; ++mi) {
        const int ml = mi * 16 + l16;
        af[mi] = *(const f16x8*)&sA[ml * 64 + ((c ^ (ml & 7)) * 8)];
      }
#pragma unroll
      for (int ni = 0; ni < 4; ++ni) {
        const int nl = wave * 64 + ni * 16 + l16;
        bf[ni] = *(const f16x8*)&sB[nl * 64 + ((c ^ (nl & 7)) * 8)];
      }
#pragma unroll
      for (int mi = 0; mi < 2; ++mi)
#pragma unroll
        for (int ni = 0; ni < 4; ++ni)
          acc[mi][ni] = __builtin_amdgcn_mfma_f32_16x16x32_f16(
              af[mi], bf[ni], acc[mi][ni], 0, 0, 0);
    }
  }
#pragma unroll
  for (int ni = 0; ni < 4; ++ni) {
    const int nc = wave * 64 + ni * 16 + l16;
    const float bv = s1b[nc];
#pragma unroll
    for (int mi = 0; mi < 2; ++mi)
#pragma unroll
      for (int r = 0; r < 4; ++r) {
        const int row = mi * 16 + quad * 4 + r;
        zs[row * 264 + nc] = (f16)fmaxf(acc[mi][ni][r] + bv, 0.0f);
      }
  }
  __syncthreads();

  // ---- GEMM2: z2[32][128] = relu(z1 @ S2T^T + s2b); wave = 32x32 ----
  f32x4 acc2[2][2];
#pragma unroll
  for (int i = 0; i < 2; ++i)
#pragma unroll
    for (int j = 0; j < 2; ++j) acc2[i][j] = (f32x4){0.f, 0.f, 0.f, 0.f};

  for (int kt2 = 0; kt2 < 4; ++kt2) {
    __syncthreads();
#pragma unroll
    for (int j = 0; j < 4; ++j) {   // B2: 128x64 halfs = 1024 chunks
      const int linear = j * 256 + tid;
      const int row = linear >> 3;
      const int q   = (linear & 7) ^ (row & 7);
      async_cp16(S2T + (size_t)row * 256 + kt2 * 64 + q * 8, &sB2[linear * 8]);
    }
    __syncthreads();
#pragma unroll
    for (int kk = 0; kk < 2; ++kk) {
      const int c = quad + kk * 4;
      f16x8 af[2], bf[2];
#pragma unroll
      for (int mi = 0; mi < 2; ++mi) {
        const int row = mi * 16 + l16;
        af[mi] = *(const f16x8*)&zs[row * 264 + (kt2 * 8 + c) * 8];
      }
#pragma unroll
      for (int ni = 0; ni < 2; ++ni) {
        const int nl = wave * 32 + ni * 16 + l16;
        bf[ni] = *(const f16x8*)&sB2[nl * 64 + ((c ^ (nl & 7)) * 8)];
      }
#pragma unroll
      for (int mi = 0; mi < 2; ++mi)
#pragma unroll
        for (int ni = 0; ni < 2; ++ni)
          acc2[mi][ni] = __builtin_amdgcn_mfma_f32_16x16x32_f16(
              af[mi], bf[ni], acc2[mi][ni], 0, 0, 0);
    }
  }
  __syncthreads();
#pragma unroll
  for (int ni = 0; ni < 2; ++ni) {
    const int nc = wave * 32 + ni * 16 + l16;
    const float bv = s2b[nc];
#pragma unroll
    for (int mi = 0; mi < 2; ++mi)
#pragma unroll
      for (int r = 0; r < 4; ++r) {
        const int row = mi * 16 + quad * 4 + r;
        z2s[row * 136 + nc] = (f16)fmaxf(acc2[mi][ni][r] + bv, 0.0f);
      }
  }
  __syncthreads();

  // ---- out[m] = sigmoid(dot(z2[m,:128], w) + b), 8 threads/row ----
  const int m  = tid >> 3;
  const int qd = tid & 7;
  float p = 0.f;
#pragma unroll
  for (int j = 0; j < 2; ++j) {
    f16x8 v = *(const f16x8*)&z2s[m * 136 + qd * 16 + j * 8];
#pragma unroll
    for (int e = 0; e < 8; ++e) p += (float)v[e] * s3w[qd * 16 + j * 8 + e];
  }
  p += __shfl_xor(p, 1);
  p += __shfl_xor(p, 2);
  p += __shfl_xor(p, 4);
  if (qd == 0) out[m0 + m] = 1.0f / (1.0f + expf(-(p + s3b[0])));
}

// ---------------------------------------------------------------------------
// Prep: 64x64 LDS tile-transposes of all weights (coalesced both sides).
// ---------------------------------------------------------------------------
__global__ __launch_bounds__(256) void prep_kernel(
    const float* __restrict__ Wp, f16* __restrict__ WpT,
    const float* __restrict__ gW, f16* __restrict__ GT,
    const float* __restrict__ s1W, f16* __restrict__ S1T,
    const float* __restrict__ s2W, f16* __restrict__ S2T)
{
  __shared__ f16 s[64 * 68];
  const int tid = threadIdx.x;
  int b = blockIdx.x;

  const float* W; f16* WT; int K, N, tile;
  if (b < 128)      { W = Wp;  WT = WpT; K = 1024; N = 512; tile = b; }
  else if (b < 320) { const int i = (b - 128) >> 6;
                      W = gW + (size_t)i * 262144; WT = GT + (size_t)i * 262144;
                      K = 512; N = 512; tile = (b - 128) & 63; }
  else if (b < 352) { W = s1W; WT = S1T; K = 512; N = 256; tile = b - 320; }
  else              { W = s2W; WT = S2T; K = 256; N = 128; tile = b - 352; }

  const int nt = tile % (N >> 6);
  const int kt = tile / (N >> 6);
#pragma unroll
  for (int it = 0; it < 16; ++it) {
    const int i  = it * 256 + tid;
    const int rk = i >> 6, rn = i & 63;
    s[rn * 68 + rk] = (f16)W[(size_t)(kt * 64 + rk) * N + nt * 64 + rn];
  }
  __syncthreads();
#pragma unroll
  for (int it = 0; it < 16; ++it) {
    const int i  = it * 256 + tid;
    const int rn = i >> 6, rk = i & 63;
    WT[(size_t)(nt * 64 + rn) * K + kt * 64 + rk] = s[rn * 68 + rk];
  }
}

// ---------------------------------------------------------------------------
extern "C" void kernel_launch(void* const* d_in, const int* in_sizes, int n_in,
                              void* d_out, int out_size, void* d_ws, size_t ws_size,
                              hipStream_t stream) {
  (void)in_sizes; (void)n_in; (void)out_size; (void)ws_size;
  const float* x   = (const float*)d_in[0];
  const float* Wp  = (const float*)d_in[1];
  const float* bp  = (const float*)d_in[2];
  const float* gW  = (const float*)d_in[3];
  const float* gb  = (const float*)d_in[4];
  const float* s1W = (const float*)d_in[5];
  const float* s1b = (const float*)d_in[6];
  const float* s2W = (const float*)d_in[7];
  const float* s2b = (const float*)d_in[8];
  const float* s3W = (const float*)d_in[9];
  const float* s3b = (const float*)d_in[10];
  float* out = (float*)d_out;

  constexpr int M = 16384;
  char* ws = (char*)d_ws;
  f16* hA  = (f16*)(ws + 0);            // 16384x512
  f16* hB  = (f16*)(ws + 16777216);     // 16384x512
  f16* WpT = (f16*)(ws + 33554432);     // [512,1024]
  f16* GT  = (f16*)(ws + 34603008);     // 3x[512,512]
  f16* S1T = (f16*)(ws + 36175872);     // [256,512]
  f16* S2T = (f16*)(ws + 36438016);     // [128,256]

  prep_kernel<<<360, 256, 0, stream>>>(Wp, WpT, gW, GT, s1W, S1T, s2W, S2T);

  // proj: hA = x @ Wp + bp  (2-phase dbuf, R17-measured ~25us)
  proj_gemm_kernel<64, 256, false, true>
      <<<dim3(M / 64, 2), 512, 0, stream>>>(x, WpT, hA, bp, M, 512, 1024);

  // GCN layers: 128x128, all-gl_lds staging + counted-vmcnt 2-phase
  gcn_gemm_kernel<true>
      <<<dim3(M / 128, 4), 256, 0, stream>>>(hA, GT, hB, gb, M);
  gcn_gemm_kernel<true>
      <<<dim3(M / 128, 4), 256, 0, stream>>>(hB, GT + 262144, hA, gb + 512, M);
  gcn_gemm_kernel<false>
      <<<dim3(M / 128, 4), 256, 0, stream>>>(hA, GT + 524288, hB, gb + 1024, M);

  head_fused_kernel<<<M / 32, 256, 0, stream>>>(hB, S1T, S2T, s1b, s2b, s3W, s3b, out);
}

// Round 16
// 197.112 us; speedup vs baseline: 2.9605x; 1.0076x over previous
//
#include <hip/hip_runtime.h>
#include <hip/hip_fp16.h>
#include <cstdint>
#include <cstddef>

// VideoSAGE: prep -> proj GEMM -> 3x GCN GEMM -> fused head. fp16 MFMA.
// R9/R10 (198us): 64x256 proj + halo-LDS band-blend GCN.
// R17 PM: dbuf-with-__syncthreads proj = 43.2us == R4's 43.8 (the vmcnt(0)
//   drain at __syncthreads nullifies the dbuf). GCN regressed via spills.
// R18/R19 PM (198.6): GCN all-gl_lds + counted-vmcnt WORKED (48.5 -> <42,
//   clean WRITE). Proj now the largest visible kernel: 43.2us, 6450 cyc/step
//   vs ~3300 byte-service + ~320 MFMA -> half of every step is exposed drain.
// R20: port counted-vmcnt to proj (keep reg-path A for fp32->f16 cvt):
//   stage(t+1)=pa-loads+B-gl_lds (6 vmem/thread) -> vmcnt(6) (t drained,
//   t+1 in flight ACROSS barrier) -> s_barrier -> sched_barrier(0) ->
//   compute(t) -> writeA(t+1) (pa reg-waits land after MFMAs) -> lgkmcnt(0)
//   -> s_barrier. GCN/head/prep byte-identical to R19.
// Falsifiers: proj 25-30us, MfmaUtil ~22-25%, WRITE ~16.4MB, total ~183-188.
//   If proj unchanged -> ~29 B/cyc/CU ingress is the binding ceiling ->
//   practical roofline.

typedef _Float16 f16;
typedef _Float16 f16x8 __attribute__((ext_vector_type(8)));
typedef float    f32x4 __attribute__((ext_vector_type(4)));

__device__ __forceinline__ void async_cp16(const void* g, void* l) {
  __builtin_amdgcn_global_load_lds((const __attribute__((address_space(1))) void*)g,
                                   (__attribute__((address_space(3))) void*)l, 16, 0, 0);
}

__device__ __forceinline__ f16x8 splat8(f16 v) {
  f16x8 r;
#pragma unroll
  for (int e = 0; e < 8; ++e) r[e] = v;
  return r;
}

// ---------------------------------------------------------------------------
// Proj GEMM: C[M,N] = A(fp32)*BT^T + bias, cvt fp32->f16 in A staging.
// BM=64, BN=256, 512 thr (2x4 waves), grid (M/64, 2) = 512 = 2/CU.
// R20: counted-vmcnt 2-phase dbuf (raw barriers), LDS 80KB = 2 blocks/CU.
// ---------------------------------------------------------------------------
template<int BM, int BN, bool RELU, bool HAS_BIAS>
__global__ __launch_bounds__(512, 2) void proj_gemm_kernel(
    const float* __restrict__ Aptr, const f16* __restrict__ BT,
    f16* __restrict__ C, const float* __restrict__ bias,
    int M, int N, int K)
{
  constexpr int BK = 64;
  constexpr int NT = 512;
  constexpr int WAVES_N = 4;
  constexpr int WM = BM / 2;         // 32
  constexpr int WN = BN / WAVES_N;   // 64
  constexpr int TM = WM / 16;        // 2
  constexpr int TN = WN / 16;        // 4
  constexpr int ITER_B = (BN * BK) / (NT * 8);   // 4

  __shared__ __align__(16) f16 sA[2][BM * BK];   // 2x8KB
  __shared__ __align__(16) f16 sB[2][BN * BK];   // 2x32KB

  const int tid  = threadIdx.x;
  const int lane = tid & 63;
  const int wave = tid >> 6;
  const int wm   = wave / WAVES_N;
  const int wn   = wave % WAVES_N;
  const int m0   = blockIdx.x * BM;
  const int n0   = blockIdx.y * BN;
  const int quad = lane >> 4;
  const int l16  = lane & 15;

  uint32_t offA;
  {
    const int row = tid >> 3;
    const int q   = (tid & 7) ^ (row & 7);
    offA = (uint32_t)(((size_t)(m0 + row) * K + q * 8) * 4);
  }

  f32x4 acc[TM][TN];
#pragma unroll
  for (int i = 0; i < TM; ++i)
#pragma unroll
    for (int j = 0; j < TN; ++j)
      acc[i][j] = (f32x4){0.f, 0.f, 0.f, 0.f};

  float4 pa0, pa1;

  auto loadA = [&](int kt) {
    const float4* p = (const float4*)((const char*)Aptr + (size_t)kt * 4 + offA);
    pa0 = p[0]; pa1 = p[1];
  };
  auto stageB = [&](int kt, int b) {
#pragma unroll
    for (int j = 0; j < ITER_B; ++j) {
      const int linear = j * NT + tid;
      const int row = linear >> 3;
      const int q   = (linear & 7) ^ (row & 7);
      async_cp16(BT + (size_t)(n0 + row) * K + kt + q * 8, &sB[b][linear * 8]);
    }
  };
  auto writeA = [&](int b) {
    f16x8 o;
    o[0] = (f16)pa0.x; o[1] = (f16)pa0.y; o[2] = (f16)pa0.z; o[3] = (f16)pa0.w;
    o[4] = (f16)pa1.x; o[5] = (f16)pa1.y; o[6] = (f16)pa1.z; o[7] = (f16)pa1.w;
    *(f16x8*)&sA[b][(size_t)tid * 8] = o;
  };
  auto compute = [&](int b) {
#pragma unroll
    for (int kk = 0; kk < 2; ++kk) {
      const int c = quad + kk * 4;
      f16x8 af[TM], bf[TN];
#pragma unroll
      for (int mi = 0; mi < TM; ++mi) {
        const int ml = wm * WM + mi * 16 + l16;
        af[mi] = *(const f16x8*)&sA[b][ml * 64 + ((c ^ (ml & 7)) * 8)];
      }
#pragma unroll
      for (int ni = 0; ni < TN; ++ni) {
        const int nl = wn * WN + ni * 16 + l16;
        bf[ni] = *(const f16x8*)&sB[b][nl * 64 + ((c ^ (nl & 7)) * 8)];
      }
#pragma unroll
      for (int mi = 0; mi < TM; ++mi)
#pragma unroll
        for (int ni = 0; ni < TN; ++ni)
          acc[mi][ni] = __builtin_amdgcn_mfma_f32_16x16x32_f16(
              af[mi], bf[ni], acc[mi][ni], 0, 0, 0);
    }
  };

  // ---- prologue: tile 0 fully staged (latency exposed once) ----
  loadA(0);
  stageB(0, 0);
  writeA(0);                 // compiler waits pa regs
  __syncthreads();           // full drain (vmcnt+lgkm) + barrier

  const int nt = K / BK;
  for (int t = 0; t < nt; ++t) {
    const int cur = t & 1;
    const bool pf = (t + 1 < nt);
    if (pf) {
      loadA((t + 1) * BK);                 // 2 vmem (regs)
      stageB((t + 1) * BK, cur ^ 1);       // 4 vmem (gl_lds)
      asm volatile("s_waitcnt vmcnt(6)" ::: "memory");  // drain t, keep t+1
    } else {
      asm volatile("s_waitcnt vmcnt(0)" ::: "memory");
    }
    asm volatile("s_barrier" ::: "memory");     // tile t ready in LDS
    __builtin_amdgcn_sched_barrier(0);
    compute(cur);
    if (pf) {
      writeA(cur ^ 1);                          // pa waits land after MFMAs
      asm volatile("s_waitcnt lgkmcnt(0)" ::: "memory");  // ds_write visible
    }
    asm volatile("s_barrier" ::: "memory");     // tile t consumed
  }

#pragma unroll
  for (int ni = 0; ni < TN; ++ni) {
    const int nc = n0 + wn * WN + ni * 16 + l16;
    const float bv = HAS_BIAS ? bias[nc] : 0.0f;
#pragma unroll
    for (int mi = 0; mi < TM; ++mi) {
#pragma unroll
      for (int r = 0; r < 4; ++r) {
        const int mr = m0 + wm * WM + mi * 16 + quad * 4 + r;
        float v = acc[mi][ni][r] + bv;
        if (RELU) v = fmaxf(v, 0.0f);
        C[(size_t)mr * N + nc] = (f16)v;
      }
    }
  }
}

// ---------------------------------------------------------------------------
// GCN GEMM (one layer): C = act(band(h) @ W + b). 128x128, BK=64, 256 thr /
// 4 waves (2x2), wave 64x64 (TM=4,TN=4). R18: all-gl_lds staging of 130 rows
// (ldsrow r <-> global m0-1+r), counted-vmcnt 2-phase dbuf, raw barriers.
// 9 vmem/stage/wave uniform. LDS 64.5KB -> 2 blocks/CU = grid (M/128,4)=512.
// PROVEN on HW in R19 (passed, <42us, clean WRITE) -- byte-identical here.
// ---------------------------------------------------------------------------
template<bool RELU>
__global__ __launch_bounds__(256, 2) void gcn_gemm_kernel(
    const f16* __restrict__ hin, const f16* __restrict__ WT,
    f16* __restrict__ C, const float* __restrict__ bias, int M)
{
  constexpr int BM = 128, BN = 128, BK = 64;
  constexpr int NT = 256;
  constexpr int TM = 4, TN = 4;
  constexpr int S = 2048, H = 512;
  constexpr int AROWS = BM + 2;      // 130

  __shared__ __align__(16) f16 sA[2][AROWS * BK];   // 2x16.25KB
  __shared__ __align__(16) f16 sB[2][BN * BK];      // 2x16KB

  const int tid  = threadIdx.x;
  const int lane = tid & 63;
  const int wave = tid >> 6;         // 0..3
  const int wm   = wave >> 1;        // 0..1
  const int wn   = wave & 1;         // 0..1
  const int quad = lane >> 4;
  const int l16  = lane & 15;
  const int m0   = blockIdx.x * BM;
  const int n0   = blockIdx.y * BN;

  const float dM = 0.57735026919f;   // (3+1e-8)^-1/2
  const float dE = 0.70710678118f;   // (2+1e-8)^-1/2

  // per-lane tridiag coefs for the TM A-fragment rows
  f16 cf[TM][3];
#pragma unroll
  for (int mi = 0; mi < TM; ++mi) {
    const int grow = m0 + wm * 64 + mi * 16 + l16;
    const int s = grow & (S - 1);
    const float dsv = (s == 0 || s == S - 1) ? dE : dM;
    cf[mi][0] = (f16)((s > 0)     ? dsv * ((s - 1 == 0) ? dE : dM)     : 0.0f);
    cf[mi][1] = (f16)(dsv * dsv);
    cf[mi][2] = (f16)((s < S - 1) ? dsv * ((s + 1 == S - 1) ? dE : dM) : 0.0f);
  }

  // ---- precomputed element offsets (uint32; buffers < 2^32 elems) ----
  uint32_t offB[4], offA[4], offH;
#pragma unroll
  for (int j = 0; j < 4; ++j) {
    const int linear = j * NT + tid;
    const int row = linear >> 3;
    const int q   = (linear & 7) ^ (row & 7);
    offB[j] = (uint32_t)((size_t)(n0 + row) * H + q * 8);
  }
#pragma unroll
  for (int j = 0; j < 4; ++j) {
    const int c = j * NT + tid;          // chunks 0..1023 -> ldsrows 0..127
    const int r = c >> 3;
    const int q = (c & 7) ^ (r & 7);
    int g = m0 - 1 + r;
    g = g < 0 ? 0 : (g >= M ? M - 1 : g);
    offA[j] = (uint32_t)((size_t)g * H + q * 8);
  }
  {
    const int c = 1024 + (lane & 15);    // ldsrows 128,129 (lanes<16 only)
    const int r = c >> 3;
    const int q = (c & 7) ^ (r & 7);
    int g = m0 - 1 + r;
    g = g < 0 ? 0 : (g >= M ? M - 1 : g);
    offH = (uint32_t)((size_t)g * H + q * 8);
  }

  auto stage = [&](int kt, int b) {
#pragma unroll
    for (int j = 0; j < 4; ++j)
      async_cp16(WT + (size_t)offB[j] + kt, &sB[b][(j * NT + tid) * 8]);
#pragma unroll
    for (int j = 0; j < 4; ++j)
      async_cp16(hin + (size_t)offA[j] + kt, &sA[b][(j * NT + tid) * 8]);
    if (lane < 16)   // all 4 waves issue (same bytes -> benign; count uniform)
      async_cp16(hin + (size_t)offH + kt, &sA[b][(1024 + lane) * 8]);
  };

  f32x4 acc[TM][TN];
#pragma unroll
  for (int i = 0; i < TM; ++i)
#pragma unroll
    for (int j = 0; j < TN; ++j)
      acc[i][j] = (f32x4){0.f, 0.f, 0.f, 0.f};

  auto compute = [&](int b) {
#pragma unroll
    for (int kk = 0; kk < 2; ++kk) {
      const int c = quad + kk * 4;
      f16x8 af[TM], bf[TN];
#pragma unroll
      for (int mi = 0; mi < TM; ++mi) {
        const int ldr = wm * 64 + mi * 16 + l16 + 1;   // 1..128
        f16x8 pv = *(const f16x8*)&sA[b][(ldr - 1) * 64 + ((c ^ ((ldr - 1) & 7)) * 8)];
        f16x8 sv = *(const f16x8*)&sA[b][(ldr    ) * 64 + ((c ^ ((ldr    ) & 7)) * 8)];
        f16x8 nv = *(const f16x8*)&sA[b][(ldr + 1) * 64 + ((c ^ ((ldr + 1) & 7)) * 8)];
        f16x8 r = pv * splat8(cf[mi][0]);
        r += sv * splat8(cf[mi][1]);
        r += nv * splat8(cf[mi][2]);
        af[mi] = r;
      }
#pragma unroll
      for (int ni = 0; ni < TN; ++ni) {
        const int nl = wn * 64 + ni * 16 + l16;
        bf[ni] = *(const f16x8*)&sB[b][nl * 64 + ((c ^ (nl & 7)) * 8)];
      }
#pragma unroll
      for (int mi = 0; mi < TM; ++mi)
#pragma unroll
        for (int ni = 0; ni < TN; ++ni)
          acc[mi][ni] = __builtin_amdgcn_mfma_f32_16x16x32_f16(
              af[mi], bf[ni], acc[mi][ni], 0, 0, 0);
    }
  };

  // ---- counted-vmcnt 2-phase loop ----
  stage(0, 0);                           // 9 outstanding
  constexpr int NTILES = H / BK;         // 8
  for (int t = 0; t < NTILES; ++t) {
    const int cur = t & 1;
    if (t + 1 < NTILES) {
      stage((t + 1) * BK, cur ^ 1);      // 18 outstanding
      asm volatile("s_waitcnt vmcnt(9)" ::: "memory");   // drain t, keep t+1
    } else {
      asm volatile("s_waitcnt vmcnt(0)" ::: "memory");
    }
    asm volatile("s_barrier" ::: "memory");    // all waves: tile t ready
    __builtin_amdgcn_sched_barrier(0);
    compute(cur);
    asm volatile("s_barrier" ::: "memory");    // tile t fully consumed
  }

#pragma unroll
  for (int ni = 0; ni < TN; ++ni) {
    const int nc = n0 + wn * 64 + ni * 16 + l16;
    const float bv = bias[nc];
#pragma unroll
    for (int mi = 0; mi < TM; ++mi) {
#pragma unroll
      for (int r = 0; r < 4; ++r) {
        const int mr = m0 + wm * 64 + mi * 16 + quad * 4 + r;
        float v = acc[mi][ni][r] + bv;
        if (RELU) v = fmaxf(v, 0.0f);
        C[(size_t)mr * H + nc] = (f16)v;
      }
    }
  }
}

// ---------------------------------------------------------------------------
// Fused head, 32 rows/block (512 blocks): z1[32][256] LDS -> z2[32][128] LDS
// -> sigmoid dot. Total ~53.8KB -> 2 blocks/CU.
// ---------------------------------------------------------------------------
__global__ __launch_bounds__(256) void head_fused_kernel(
    const f16* __restrict__ h, const f16* __restrict__ S1T,
    const f16* __restrict__ S2T,
    const float* __restrict__ s1b, const float* __restrict__ s2b,
    const float* __restrict__ s3w, const float* __restrict__ s3b,
    float* __restrict__ out)
{
  __shared__ __align__(16) char smem[36864 + 32 * 264 * 2];
  f16* sA  = (f16*)smem;             // [32*64]   = 4KB
  f16* sB  = (f16*)(smem + 4096);    // [256*64]  = 32KB
  f16* zs  = (f16*)(smem + 36864);   // [32][264]
  f16* z2s = (f16*)smem;             // [32][136] = 8.5KB (reuses sA+sB head)
  f16* sB2 = (f16*)(smem + 8704);    // [128*64]  = 16KB

  const int tid  = threadIdx.x;
  const int lane = tid & 63;
  const int wave = tid >> 6;
  const int quad = lane >> 4;
  const int l16  = lane & 15;
  const int m0   = blockIdx.x * 32;

  // ---- GEMM1: z1[32][256] = relu(h[32x512] @ S1T^T + s1b); wave = 32x64 ----
  f32x4 acc[2][4];
#pragma unroll
  for (int i = 0; i < 2; ++i)
#pragma unroll
    for (int j = 0; j < 4; ++j) acc[i][j] = (f32x4){0.f, 0.f, 0.f, 0.f};

  for (int kt = 0; kt < 512; kt += 64) {
    __syncthreads();
    {   // A: 32x64 halfs = 256 chunks, 1 iter
      const int linear = tid;
      const int row = linear >> 3;
      const int q   = (linear & 7) ^ (row & 7);
      async_cp16(h + (size_t)(m0 + row) * 512 + kt + q * 8, &sA[linear * 8]);
    }
#pragma unroll
    for (int j = 0; j < 8; ++j) {   // B: 256x64 halfs = 2048 chunks
      const int linear = j * 256 + tid;
      const int row = linear >> 3;
      const int q   = (linear & 7) ^ (row & 7);
      async_cp16(S1T + (size_t)row * 512 + kt + q * 8, &sB[linear * 8]);
    }
    __syncthreads();
#pragma unroll
    for (int kk = 0; kk < 2; ++kk) {
      const int c = quad + kk * 4;
      f16x8 af[2], bf[4];
#pragma unroll
      for (int mi = 0; mi < 2; ++mi) {
        const int ml = mi * 16 + l16;
        af[mi] = *(const f16x8*)&sA[ml * 64 + ((c ^ (ml & 7)) * 8)];
      }
#pragma unroll
      for (int ni = 0; ni < 4; ++ni) {
        const int nl = wave * 64 + ni * 16 + l16;
        bf[ni] = *(const f16x8*)&sB[nl * 64 + ((c ^ (nl & 7)) * 8)];
      }
#pragma unroll
      for (int mi = 0; mi < 2; ++mi)
#pragma unroll
        for (int ni = 0; ni < 4; ++ni)
          acc[mi][ni] = __builtin_amdgcn_mfma_f32_16x16x32_f16(
              af[mi], bf[ni], acc[mi][ni], 0, 0, 0);
    }
  }
#pragma unroll
  for (int ni = 0; ni < 4; ++ni) {
    const int nc = wave * 64 + ni * 16 + l16;
    const float bv = s1b[nc];
#pragma unroll
    for (int mi = 0; mi < 2; ++mi)
#pragma unroll
      for (int r = 0; r < 4; ++r) {
        const int row = mi * 16 + quad * 4 + r;
        zs[row * 264 + nc] = (f16)fmaxf(acc[mi][ni][r] + bv, 0.0f);
      }
  }
  __syncthreads();

  // ---- GEMM2: z2[32][128] = relu(z1 @ S2T^T + s2b); wave = 32x32 ----
  f32x4 acc2[2][2];
#pragma unroll
  for (int i = 0; i < 2; ++i)
#pragma unroll
    for (int j = 0; j < 2; ++j) acc2[i][j] = (f32x4){0.f, 0.f, 0.f, 0.f};

  for (int kt2 = 0; kt2 < 4; ++kt2) {
    __syncthreads();
#pragma unroll
    for (int j = 0; j < 4; ++j) {   // B2: 128x64 halfs = 1024 chunks
      const int linear = j * 256 + tid;
      const int row = linear >> 3;
      const int q   = (linear & 7) ^ (row & 7);
      async_cp16(S2T + (size_t)row * 256 + kt2 * 64 + q * 8, &sB2[linear * 8]);
    }
    __syncthreads();
#pragma unroll
    for (int kk = 0; kk < 2; ++kk) {
      const int c = quad + kk * 4;
      f16x8 af[2], bf[2];
#pragma unroll
      for (int mi = 0; mi < 2; ++mi) {
        const int row = mi * 16 + l16;
        af[mi] = *(const f16x8*)&zs[row * 264 + (kt2 * 8 + c) * 8];
      }
#pragma unroll
      for (int ni = 0; ni < 2; ++ni) {
        const int nl = wave * 32 + ni * 16 + l16;
        bf[ni] = *(const f16x8*)&sB2[nl * 64 + ((c ^ (nl & 7)) * 8)];
      }
#pragma unroll
      for (int mi = 0; mi < 2; ++mi)
#pragma unroll
        for (int ni = 0; ni < 2; ++ni)
          acc2[mi][ni] = __builtin_amdgcn_mfma_f32_16x16x32_f16(
              af[mi], bf[ni], acc2[mi][ni], 0, 0, 0);
    }
  }
  __syncthreads();
#pragma unroll
  for (int ni = 0; ni < 2; ++ni) {
    const int nc = wave * 32 + ni * 16 + l16;
    const float bv = s2b[nc];
#pragma unroll
    for (int mi = 0; mi < 2; ++mi)
#pragma unroll
      for (int r = 0; r < 4; ++r) {
        const int row = mi * 16 + quad * 4 + r;
        z2s[row * 136 + nc] = (f16)fmaxf(acc2[mi][ni][r] + bv, 0.0f);
      }
  }
  __syncthreads();

  // ---- out[m] = sigmoid(dot(z2[m,:128], w) + b), 8 threads/row ----
  const int m  = tid >> 3;
  const int qd = tid & 7;
  float p = 0.f;
#pragma unroll
  for (int j = 0; j < 2; ++j) {
    f16x8 v = *(const f16x8*)&z2s[m * 136 + qd * 16 + j * 8];
#pragma unroll
    for (int e = 0; e < 8; ++e) p += (float)v[e] * s3w[qd * 16 + j * 8 + e];
  }
  p += __shfl_xor(p, 1);
  p += __shfl_xor(p, 2);
  p += __shfl_xor(p, 4);
  if (qd == 0) out[m0 + m] = 1.0f / (1.0f + expf(-(p + s3b[0])));
}

// ---------------------------------------------------------------------------
// Prep: 64x64 LDS tile-transposes of all weights (coalesced both sides).
// ---------------------------------------------------------------------------
__global__ __launch_bounds__(256) void prep_kernel(
    const float* __restrict__ Wp, f16* __restrict__ WpT,
    const float* __restrict__ gW, f16* __restrict__ GT,
    const float* __restrict__ s1W, f16* __restrict__ S1T,
    const float* __restrict__ s2W, f16* __restrict__ S2T)
{
  __shared__ f16 s[64 * 68];
  const int tid = threadIdx.x;
  int b = blockIdx.x;

  const float* W; f16* WT; int K, N, tile;
  if (b < 128)      { W = Wp;  WT = WpT; K = 1024; N = 512; tile = b; }
  else if (b < 320) { const int i = (b - 128) >> 6;
                      W = gW + (size_t)i * 262144; WT = GT + (size_t)i * 262144;
                      K = 512; N = 512; tile = (b - 128) & 63; }
  else if (b < 352) { W = s1W; WT = S1T; K = 512; N = 256; tile = b - 320; }
  else              { W = s2W; WT = S2T; K = 256; N = 128; tile = b - 352; }

  const int nt = tile % (N >> 6);
  const int kt = tile / (N >> 6);
#pragma unroll
  for (int it = 0; it < 16; ++it) {
    const int i  = it * 256 + tid;
    const int rk = i >> 6, rn = i & 63;
    s[rn * 68 + rk] = (f16)W[(size_t)(kt * 64 + rk) * N + nt * 64 + rn];
  }
  __syncthreads();
#pragma unroll
  for (int it = 0; it < 16; ++it) {
    const int i  = it * 256 + tid;
    const int rn = i >> 6, rk = i & 63;
    WT[(size_t)(nt * 64 + rn) * K + kt * 64 + rk] = s[rn * 68 + rk];
  }
}

// ---------------------------------------------------------------------------
extern "C" void kernel_launch(void* const* d_in, const int* in_sizes, int n_in,
                              void* d_out, int out_size, void* d_ws, size_t ws_size,
                              hipStream_t stream) {
  (void)in_sizes; (void)n_in; (void)out_size; (void)ws_size;
  const float* x   = (const float*)d_in[0];
  const float* Wp  = (const float*)d_in[1];
  const float* bp  = (const float*)d_in[2];
  const float* gW  = (const float*)d_in[3];
  const float* gb  = (const float*)d_in[4];
  const float* s1W = (const float*)d_in[5];
  const float* s1b = (const float*)d_in[6];
  const float* s2W = (const float*)d_in[7];
  const float* s2b = (const float*)d_in[8];
  const float* s3W = (const float*)d_in[9];
  const float* s3b = (const float*)d_in[10];
  float* out = (float*)d_out;

  constexpr int M = 16384;
  char* ws = (char*)d_ws;
  f16* hA  = (f16*)(ws + 0);            // 16384x512
  f16* hB  = (f16*)(ws + 16777216);     // 16384x512
  f16* WpT = (f16*)(ws + 33554432);     // [512,1024]
  f16* GT  = (f16*)(ws + 34603008);     // 3x[512,512]
  f16* S1T = (f16*)(ws + 36175872);     // [256,512]
  f16* S2T = (f16*)(ws + 36438016);     // [128,256]

  prep_kernel<<<360, 256, 0, stream>>>(Wp, WpT, gW, GT, s1W, S1T, s2W, S2T);

  // proj: hA = x @ Wp + bp  (counted-vmcnt 2-phase dbuf)
  proj_gemm_kernel<64, 256, false, true>
      <<<dim3(M / 64, 2), 512, 0, stream>>>(x, WpT, hA, bp, M, 512, 1024);

  // GCN layers: 128x128, all-gl_lds staging + counted-vmcnt 2-phase (R19)
  gcn_gemm_kernel<true>
      <<<dim3(M / 128, 4), 256, 0, stream>>>(hA, GT, hB, gb, M);
  gcn_gemm_kernel<true>
      <<<dim3(M / 128, 4), 256, 0, stream>>>(hB, GT + 262144, hA, gb + 512, M);
  gcn_gemm_kernel<false>
      <<<dim3(M / 128, 4), 256, 0, stream>>>(hA, GT + 524288, hB, gb + 1024, M);

  head_fused_kernel<<<M / 32, 256, 0, stream>>>(hB, S1T, S2T, s1b, s2b, s3W, s3b, out);
}